// Round 3
// baseline (3279.916 us; speedup 1.0000x reference)
//
#include <hip/hip_runtime.h>
#include <math.h>

#define N_NODES 50000
#define P_PATHS 4
#define E_EDGES 800000
#define IN_F 256
#define OUT_F 128
#define NPB 128                        // nodes per bucket
#define NBUCK 391                      // ceil(N/NPB)
#define NCHUNK 64                      // edge chunks per path
#define CHUNK_E (E_EDGES / NCHUNK)     // 12500
#define DEG_BLOCKS 25
#define DEG_NODES 2000                 // nodes per degout block
#define GBLK 391                       // row-blocks for gemm/fc (128 rows each)

typedef unsigned short ushort_t;
typedef unsigned int uint_t;
typedef float f32x4 __attribute__((ext_vector_type(4)));
typedef short s16x8 __attribute__((ext_vector_type(8)));

__device__ __forceinline__ ushort_t f2bf(float f) {
    uint_t u = __float_as_uint(f);
    return (ushort_t)((u + 0x7FFFu + ((u >> 16) & 1u)) >> 16);   // RNE
}
__device__ __forceinline__ float bf2f(ushort_t h) {
    return __uint_as_float(((uint_t)h) << 16);
}

// ---------------- prep: W -> Wt bf16 (transposed [p][n][k]), fc_w -> bf16 ----------------
__global__ void prep_kernel(const float* __restrict__ W, const float* __restrict__ fcw,
                            ushort_t* __restrict__ Wt, ushort_t* __restrict__ fcwb)
{
    int idx = blockIdx.x * blockDim.x + threadIdx.x;
    if (idx < P_PATHS * IN_F * OUT_F) {          // 131072
        int p = idx >> 15;
        int r = idx & 32767;
        int k = r >> 7;
        int n = r & 127;
        Wt[((size_t)p << 15) + (size_t)n * IN_F + k] = f2bf(W[idx]);
    }
    if (idx < OUT_F * OUT_F) fcwb[idx] = f2bf(fcw[idx]);
}

// ---------------- deg_out via streaming LDS histogram -> rsout = rsqrt(max(deg,1)) ----------------
__global__ __launch_bounds__(256) void degout_kernel(const int* __restrict__ src,
                                                     float* __restrict__ rsout)
{
    __shared__ uint_t cnt[DEG_NODES];
    int p = blockIdx.y;
    int base = blockIdx.x * DEG_NODES;
    int t = threadIdx.x;
    for (int i = t; i < DEG_NODES; i += 256) cnt[i] = 0;
    __syncthreads();
    const int4* s4 = (const int4*)(src + (size_t)p * E_EDGES);
    for (int i = t; i < E_EDGES / 4; i += 256) {
        int4 v = s4[i];
        uint_t r;
        r = (uint_t)(v.x - base); if (r < DEG_NODES) atomicAdd(&cnt[r], 1u);
        r = (uint_t)(v.y - base); if (r < DEG_NODES) atomicAdd(&cnt[r], 1u);
        r = (uint_t)(v.z - base); if (r < DEG_NODES) atomicAdd(&cnt[r], 1u);
        r = (uint_t)(v.w - base); if (r < DEG_NODES) atomicAdd(&cnt[r], 1u);
    }
    __syncthreads();
    for (int i = t; i < DEG_NODES; i += 256) {
        uint_t c = cnt[i];
        rsout[(size_t)p * N_NODES + base + i] = rsqrtf((float)(c ? c : 1u));
    }
}

// ---------------- bucket histogram (by dst>>7) ----------------
__global__ __launch_bounds__(256) void bhist_kernel(const int* __restrict__ dst,
                                                    uint_t* __restrict__ bcounts)
{
    __shared__ uint_t bh[NBUCK];
    int p = blockIdx.y;
    int t = threadIdx.x;
    for (int i = t; i < NBUCK; i += 256) bh[i] = 0;
    __syncthreads();
    const int4* d4 = (const int4*)(dst + (size_t)p * E_EDGES + (size_t)blockIdx.x * CHUNK_E);
    for (int i = t; i < CHUNK_E / 4; i += 256) {
        int4 v = d4[i];
        atomicAdd(&bh[v.x >> 7], 1u);
        atomicAdd(&bh[v.y >> 7], 1u);
        atomicAdd(&bh[v.z >> 7], 1u);
        atomicAdd(&bh[v.w >> 7], 1u);
    }
    __syncthreads();
    for (int i = t; i < NBUCK; i += 256)
        if (bh[i]) atomicAdd(&bcounts[p * NBUCK + i], bh[i]);
}

// ---------------- flat exclusive scan over P*NBUCK bucket counts ----------------
__global__ __launch_bounds__(1024) void bscan_kernel(const uint_t* __restrict__ bcounts,
                                                     int* __restrict__ bstart,
                                                     int* __restrict__ bcursor)
{
    __shared__ int a[2048], b[2048];
    int t = threadIdx.x;
    for (int i = t; i < 2048; i += 1024)
        a[i] = (i < P_PATHS * NBUCK) ? (int)bcounts[i] : 0;
    __syncthreads();
    int* pin = a; int* pout = b;
    for (int off = 1; off < 2048; off <<= 1) {
        for (int i = t; i < 2048; i += 1024)
            pout[i] = pin[i] + (i >= off ? pin[i - off] : 0);
        __syncthreads();
        int* tmp = pin; pin = pout; pout = tmp;
    }
    for (int i = t; i < P_PATHS * NBUCK; i += 1024) {
        int st = pin[i] - (int)bcounts[i];
        bstart[i] = st;
        bcursor[i] = st;
    }
    if (t == 0) bstart[P_PATHS * NBUCK] = pin[P_PATHS * NBUCK - 1];
}

// ---------------- scatter packed edges (src | dloc<<16) into bucket order ----------------
__global__ __launch_bounds__(256) void bscatter_kernel(const int* __restrict__ src,
                                                       const int* __restrict__ dst,
                                                       int* __restrict__ bcursor,
                                                       uint_t* __restrict__ ebuf)
{
    __shared__ uint_t bh[NBUCK];
    __shared__ uint_t lbase[NBUCK];
    int p = blockIdx.y;
    int t = threadIdx.x;
    for (int i = t; i < NBUCK; i += 256) bh[i] = 0;
    __syncthreads();
    size_t ebase = (size_t)p * E_EDGES + (size_t)blockIdx.x * CHUNK_E;
    const int4* d4 = (const int4*)(dst + ebase);
    const int4* s4 = (const int4*)(src + ebase);
    for (int i = t; i < CHUNK_E / 4; i += 256) {
        int4 v = d4[i];
        atomicAdd(&bh[v.x >> 7], 1u);
        atomicAdd(&bh[v.y >> 7], 1u);
        atomicAdd(&bh[v.z >> 7], 1u);
        atomicAdd(&bh[v.w >> 7], 1u);
    }
    __syncthreads();
    for (int i = t; i < NBUCK; i += 256) {
        uint_t c = bh[i];
        lbase[i] = c ? (uint_t)atomicAdd(&bcursor[p * NBUCK + i], (int)c) : 0u;
        bh[i] = 0;     // reuse as local cursor
    }
    __syncthreads();
    for (int i = t; i < CHUNK_E / 4; i += 256) {
        int4 d = d4[i];
        int4 s = s4[i];
        { int bk = d.x >> 7; uint_t pos = lbase[bk] + atomicAdd(&bh[bk], 1u); ebuf[pos] = (uint_t)s.x | ((uint_t)(d.x & 127) << 16); }
        { int bk = d.y >> 7; uint_t pos = lbase[bk] + atomicAdd(&bh[bk], 1u); ebuf[pos] = (uint_t)s.y | ((uint_t)(d.y & 127) << 16); }
        { int bk = d.z >> 7; uint_t pos = lbase[bk] + atomicAdd(&bh[bk], 1u); ebuf[pos] = (uint_t)s.z | ((uint_t)(d.z & 127) << 16); }
        { int bk = d.w >> 7; uint_t pos = lbase[bk] + atomicAdd(&bh[bk], 1u); ebuf[pos] = (uint_t)s.w | ((uint_t)(d.w & 127) << 16); }
    }
}

// ---------------- MFMA GEMM: xwb = bf16( (x @ Wt^T) * rsout )  [M=50000,K=256,N=128] ----------------
__global__ __launch_bounds__(256) void gemm_xw_kernel(const float* __restrict__ x,
                                                      const ushort_t* __restrict__ Wt,
                                                      const float* __restrict__ rsout,
                                                      ushort_t* __restrict__ xwb)
{
    __shared__ ushort_t As[128 * 40];
    __shared__ ushort_t Bs[128 * 40];
    int m0 = blockIdx.x * 128;
    int t = threadIdx.x;
    int wid = t >> 6, lane = t & 63;
    int wr = wid >> 1, wc = wid & 1;
    f32x4 acc[4][4] = {};
    int srow = t >> 1, half = (t & 1) * 16;
    for (int k0 = 0; k0 < IN_F; k0 += 32) {
        {   // A: 128x32 fp32 -> bf16 LDS
            int gr = m0 + srow;
            uint4 w0 = make_uint4(0, 0, 0, 0), w1 = make_uint4(0, 0, 0, 0);
            if (gr < N_NODES) {
                const float* ap = x + (size_t)gr * IN_F + k0 + half;
                float4 f0 = *(const float4*)(ap + 0);
                float4 f1 = *(const float4*)(ap + 4);
                float4 f2 = *(const float4*)(ap + 8);
                float4 f3 = *(const float4*)(ap + 12);
                w0.x = (uint_t)f2bf(f0.x) | ((uint_t)f2bf(f0.y) << 16);
                w0.y = (uint_t)f2bf(f0.z) | ((uint_t)f2bf(f0.w) << 16);
                w0.z = (uint_t)f2bf(f1.x) | ((uint_t)f2bf(f1.y) << 16);
                w0.w = (uint_t)f2bf(f1.z) | ((uint_t)f2bf(f1.w) << 16);
                w1.x = (uint_t)f2bf(f2.x) | ((uint_t)f2bf(f2.y) << 16);
                w1.y = (uint_t)f2bf(f2.z) | ((uint_t)f2bf(f2.w) << 16);
                w1.z = (uint_t)f2bf(f3.x) | ((uint_t)f2bf(f3.y) << 16);
                w1.w = (uint_t)f2bf(f3.z) | ((uint_t)f2bf(f3.w) << 16);
            }
            *(uint4*)&As[srow * 40 + half]     = w0;
            *(uint4*)&As[srow * 40 + half + 8] = w1;
        }
        {   // B: Wt rows ([n][k]) bf16 direct
            const ushort_t* bp = Wt + (size_t)srow * IN_F + k0 + half;
            *(uint4*)&Bs[srow * 40 + half]     = *(const uint4*)(bp);
            *(uint4*)&Bs[srow * 40 + half + 8] = *(const uint4*)(bp + 8);
        }
        __syncthreads();
        s16x8 aF[4], bF[4];
        int kk = (lane >> 4) * 8;
#pragma unroll
        for (int m = 0; m < 4; ++m)
            aF[m] = *(const s16x8*)&As[(wr * 64 + m * 16 + (lane & 15)) * 40 + kk];
#pragma unroll
        for (int n = 0; n < 4; ++n)
            bF[n] = *(const s16x8*)&Bs[(wc * 64 + n * 16 + (lane & 15)) * 40 + kk];
#pragma unroll
        for (int m = 0; m < 4; ++m)
#pragma unroll
            for (int n = 0; n < 4; ++n)
                acc[m][n] = __builtin_amdgcn_mfma_f32_16x16x32_bf16(aF[m], bF[n], acc[m][n], 0, 0, 0);
        __syncthreads();
    }
#pragma unroll
    for (int m = 0; m < 4; ++m) {
#pragma unroll
        for (int i = 0; i < 4; ++i) {
            int row = m0 + wr * 64 + m * 16 + (lane >> 4) * 4 + i;
            if (row < N_NODES) {
                float rs = rsout[row];
#pragma unroll
                for (int n = 0; n < 4; ++n) {
                    int col = wc * 64 + n * 16 + (lane & 15);
                    xwb[(size_t)row * OUT_F + col] = f2bf(acc[m][n][i] * rs);
                }
            }
        }
    }
}

// ---------------- bucket gather: LDS-accumulate rows, write h = agg*rsqrt(deg)+b_conv ----------------
__global__ __launch_bounds__(256) void bgather_kernel(const ushort_t* __restrict__ xwb,
                                                      const uint_t* __restrict__ ebuf,
                                                      const int* __restrict__ bstart,
                                                      const float* __restrict__ bconv,
                                                      float* __restrict__ hout,
                                                      int pbase_bucket)
{
    __shared__ float accum[NPB * OUT_F];   // 64 KB
    __shared__ uint_t cnt[NPB];
    __shared__ float scal[NPB];
    int bkt = blockIdx.x;
    int t = threadIdx.x;
    int wid = t >> 6, lane = t & 63;
    for (int i = t; i < NPB * OUT_F; i += 256) accum[i] = 0.f;
    for (int i = t; i < NPB; i += 256) cnt[i] = 0;
    __syncthreads();
    int r0 = bstart[pbase_bucket + bkt];
    int r1 = bstart[pbase_bucket + bkt + 1];
    for (int e = r0 + wid; e < r1; e += 4) {
        uint_t pk = ebuf[e];
        int s = (int)(pk & 0xFFFFu);
        int dl = (int)(pk >> 16);
        ushort_t u0 = xwb[(size_t)s * OUT_F + lane];
        ushort_t u1 = xwb[(size_t)s * OUT_F + 64 + lane];
        atomicAdd(&accum[dl * OUT_F + lane], bf2f(u0));
        atomicAdd(&accum[dl * OUT_F + 64 + lane], bf2f(u1));
        if (lane == 0) atomicAdd(&cnt[dl], 1u);
    }
    __syncthreads();
    int base = bkt * NPB;
    int nn = N_NODES - base; if (nn > NPB) nn = NPB;
    for (int i = t; i < NPB; i += 256) {
        uint_t c = cnt[i];
        scal[i] = rsqrtf((float)(c ? c : 1u));
    }
    __syncthreads();
    for (int idx = t; idx < nn * (OUT_F / 4); idx += 256) {
        int iloc = idx >> 5, j4 = (idx & 31) * 4;
        float4 a = *(const float4*)&accum[iloc * OUT_F + j4];
        float4 bc = *(const float4*)(bconv + j4);
        float sc = scal[iloc];
        float4 r;
        r.x = fmaf(a.x, sc, bc.x); r.y = fmaf(a.y, sc, bc.y);
        r.z = fmaf(a.z, sc, bc.z); r.w = fmaf(a.w, sc, bc.w);
        *(float4*)(hout + (size_t)(base + iloc) * OUT_F + j4) = r;
    }
}

// ---------------- MFMA fc + tanh + per-block column sums ----------------
__global__ __launch_bounds__(256) void fc_mfma_kernel(const float* __restrict__ h,
                                                      const ushort_t* __restrict__ fcwb,
                                                      const float* __restrict__ fcb,
                                                      float* __restrict__ partial)
{
    __shared__ ushort_t As[128 * 40];
    __shared__ ushort_t Bs[128 * 40];
    __shared__ float red[2][128];
    int m0 = blockIdx.x * 128;
    int t = threadIdx.x;
    int wid = t >> 6, lane = t & 63;
    int wr = wid >> 1, wc = wid & 1;
    f32x4 acc[4][4] = {};
    int srow = t >> 1, half = (t & 1) * 16;
    for (int k0 = 0; k0 < OUT_F; k0 += 32) {
        {
            int gr = m0 + srow;
            uint4 w0 = make_uint4(0, 0, 0, 0), w1 = make_uint4(0, 0, 0, 0);
            if (gr < N_NODES) {
                const float* ap = h + (size_t)gr * OUT_F + k0 + half;
                float4 f0 = *(const float4*)(ap + 0);
                float4 f1 = *(const float4*)(ap + 4);
                float4 f2 = *(const float4*)(ap + 8);
                float4 f3 = *(const float4*)(ap + 12);
                w0.x = (uint_t)f2bf(f0.x) | ((uint_t)f2bf(f0.y) << 16);
                w0.y = (uint_t)f2bf(f0.z) | ((uint_t)f2bf(f0.w) << 16);
                w0.z = (uint_t)f2bf(f1.x) | ((uint_t)f2bf(f1.y) << 16);
                w0.w = (uint_t)f2bf(f1.z) | ((uint_t)f2bf(f1.w) << 16);
                w1.x = (uint_t)f2bf(f2.x) | ((uint_t)f2bf(f2.y) << 16);
                w1.y = (uint_t)f2bf(f2.z) | ((uint_t)f2bf(f2.w) << 16);
                w1.z = (uint_t)f2bf(f3.x) | ((uint_t)f2bf(f3.y) << 16);
                w1.w = (uint_t)f2bf(f3.z) | ((uint_t)f2bf(f3.w) << 16);
            }
            *(uint4*)&As[srow * 40 + half]     = w0;
            *(uint4*)&As[srow * 40 + half + 8] = w1;
        }
        {   // fcw[o][k] row-major is already [n][k]
            const ushort_t* bp = fcwb + (size_t)srow * OUT_F + k0 + half;
            *(uint4*)&Bs[srow * 40 + half]     = *(const uint4*)(bp);
            *(uint4*)&Bs[srow * 40 + half + 8] = *(const uint4*)(bp + 8);
        }
        __syncthreads();
        s16x8 aF[4], bF[4];
        int kk = (lane >> 4) * 8;
#pragma unroll
        for (int m = 0; m < 4; ++m)
            aF[m] = *(const s16x8*)&As[(wr * 64 + m * 16 + (lane & 15)) * 40 + kk];
#pragma unroll
        for (int n = 0; n < 4; ++n)
            bF[n] = *(const s16x8*)&Bs[(wc * 64 + n * 16 + (lane & 15)) * 40 + kk];
#pragma unroll
        for (int m = 0; m < 4; ++m)
#pragma unroll
            for (int n = 0; n < 4; ++n)
                acc[m][n] = __builtin_amdgcn_mfma_f32_16x16x32_bf16(aF[m], bF[n], acc[m][n], 0, 0, 0);
        __syncthreads();
    }
#pragma unroll
    for (int n = 0; n < 4; ++n) {
        int col = wc * 64 + n * 16 + (lane & 15);
        float fb = fcb[col];
        float s = 0.f;
#pragma unroll
        for (int m = 0; m < 4; ++m)
#pragma unroll
            for (int i = 0; i < 4; ++i) {
                int row = m0 + wr * 64 + m * 16 + (lane >> 4) * 4 + i;
                if (row < N_NODES) s += tanhf(acc[m][n][i] + fb);
            }
        s += __shfl_xor(s, 16);
        s += __shfl_xor(s, 32);
        if (lane < 16) red[wr][col] = s;
    }
    __syncthreads();
    if (t < 128)
        partial[(size_t)blockIdx.x * OUT_F + t] = red[0][t] + red[1][t];
}

// ---------------- reduce partials -> sp -> beta softmax ----------------
__global__ __launch_bounds__(512) void beta_reduce_kernel(const float* __restrict__ partial,
                                                          const float* __restrict__ att,
                                                          float* __restrict__ beta)
{
    int t = threadIdx.x;          // 512 = P*128
    int p = t >> 7, c = t & 127;
    float s = 0.f;
    for (int i = 0; i < GBLK; ++i)
        s += partial[((size_t)p * GBLK + i) * OUT_F + c];
    float v = att[p * OUT_F + c] * (s * (1.0f / N_NODES));
    __shared__ float red[512];
    red[t] = v;
    __syncthreads();
    for (int off = 64; off >= 1; off >>= 1) {
        if (c < off) red[t] += red[t + off];
        __syncthreads();
    }
    if (t == 0) {
        float w[P_PATHS], mx = -1e30f;
        for (int q = 0; q < P_PATHS; ++q) { w[q] = red[q * 128]; mx = fmaxf(mx, w[q]); }
        float sum = 0.f;
        for (int q = 0; q < P_PATHS; ++q) { w[q] = expf(w[q] - mx); sum += w[q]; }
        for (int q = 0; q < P_PATHS; ++q) beta[q] = w[q] / sum;
    }
}

// ---------------- out = sum_p beta[p]*h[p] + h_bias ----------------
__global__ void combine_kernel(const float* __restrict__ h, const float* __restrict__ hbias,
                               const float* __restrict__ beta, float* __restrict__ out)
{
    int idx = blockIdx.x * blockDim.x + threadIdx.x;
    if (idx >= N_NODES * (OUT_F / 4)) return;
    int n = idx >> 5;
    int j4 = (idx & 31) * 4;
    float4 hb = *(const float4*)(hbias + j4);
    float4 r = hb;
#pragma unroll
    for (int p = 0; p < P_PATHS; ++p) {
        float bp = beta[p];
        float4 a = *(const float4*)(h + ((size_t)p * N_NODES + n) * OUT_F + j4);
        r.x = fmaf(bp, a.x, r.x); r.y = fmaf(bp, a.y, r.y);
        r.z = fmaf(bp, a.z, r.z); r.w = fmaf(bp, a.w, r.w);
    }
    *(float4*)(out + (size_t)idx * 4) = r;
}

extern "C" void kernel_launch(void* const* d_in, const int* in_sizes, int n_in,
                              void* d_out, int out_size, void* d_ws, size_t ws_size,
                              hipStream_t stream)
{
    const float* x      = (const float*)d_in[0];
    const float* W      = (const float*)d_in[1];
    const float* b_conv = (const float*)d_in[2];
    const float* att    = (const float*)d_in[3];
    const float* fc_w   = (const float*)d_in[4];
    const float* fc_b   = (const float*)d_in[5];
    const float* h_bias = (const float*)d_in[6];
    const int*   src    = (const int*)d_in[7];
    const int*   dst    = (const int*)d_in[8];
    float* out = (float*)d_out;
    float* ws  = (float*)d_ws;

    // ---- ws layout (float units) ----  total ~130 MB (proven budget >= 136 MB)
    size_t off_h       = 0;                                           // P*N*128
    size_t off_rsout   = off_h + (size_t)P_PATHS * N_NODES * OUT_F;   // P*N
    size_t off_partial = off_rsout + (size_t)P_PATHS * N_NODES;       // P*GBLK*128
    size_t off_beta    = off_partial + (size_t)P_PATHS * GBLK * OUT_F;
    size_t off_i32     = (off_beta + 4 + 63) & ~(size_t)63;
    // int region
    size_t i_bstart  = 0;                                 // P*NBUCK+1 -> pad 1568
    size_t i_bcursor = 1568;                              // P*NBUCK   -> pad to 3136
    size_t i_bcounts = 3136;                              // P*NBUCK
    size_t i_ebuf    = 4704;                              // P*E
    size_t n_ints    = i_ebuf + (size_t)P_PATHS * E_EDGES;
    size_t off_u16   = off_i32 + ((n_ints + 63) & ~(size_t)63);
    // ushort region
    size_t u_xwb  = 0;                                    // N*128
    size_t u_Wt   = u_xwb + (size_t)N_NODES * OUT_F;      // P*IN*OUT
    size_t u_fcwb = u_Wt + (size_t)P_PATHS * IN_F * OUT_F;

    float* h       = ws + off_h;
    float* rsout   = ws + off_rsout;
    float* partial = ws + off_partial;
    float* beta    = ws + off_beta;
    int*   ibase   = (int*)(ws + off_i32);
    int*    bstart  = ibase + i_bstart;
    int*    bcursor = ibase + i_bcursor;
    uint_t* bcounts = (uint_t*)(ibase + i_bcounts);
    uint_t* ebuf    = (uint_t*)(ibase + i_ebuf);
    ushort_t* ubase = (ushort_t*)(ws + off_u16);
    ushort_t* xwb  = ubase + u_xwb;
    ushort_t* Wt   = ubase + u_Wt;
    ushort_t* fcwb = ubase + u_fcwb;

    // only the bucket counters accumulate -> zero each call
    hipMemsetAsync(bcounts, 0, (size_t)P_PATHS * NBUCK * sizeof(uint_t), stream);

    prep_kernel<<<(P_PATHS * IN_F * OUT_F + 255) / 256, 256, 0, stream>>>(W, fc_w, Wt, fcwb);
    degout_kernel<<<dim3(DEG_BLOCKS, P_PATHS), 256, 0, stream>>>(src, rsout);
    bhist_kernel<<<dim3(NCHUNK, P_PATHS), 256, 0, stream>>>(dst, bcounts);
    bscan_kernel<<<1, 1024, 0, stream>>>(bcounts, bstart, bcursor);
    bscatter_kernel<<<dim3(NCHUNK, P_PATHS), 256, 0, stream>>>(src, dst, bcursor, ebuf);

    for (int p = 0; p < P_PATHS; ++p) {
        gemm_xw_kernel<<<GBLK, 256, 0, stream>>>(
            x, Wt + ((size_t)p << 15), rsout + (size_t)p * N_NODES, xwb);
        bgather_kernel<<<NBUCK, 256, 0, stream>>>(
            xwb, ebuf, bstart, b_conv + p * OUT_F,
            h + (size_t)p * N_NODES * OUT_F, p * NBUCK);
        fc_mfma_kernel<<<GBLK, 256, 0, stream>>>(
            h + (size_t)p * N_NODES * OUT_F, fcwb, fc_b,
            partial + (size_t)p * GBLK * OUT_F);
    }
    beta_reduce_kernel<<<1, 512, 0, stream>>>(partial, att, beta);
    combine_kernel<<<(N_NODES * (OUT_F / 4) + 255) / 256, 256, 0, stream>>>(
        h, h_bias, beta, out);
}

// Round 4
// 703.266 us; speedup vs baseline: 4.6638x; 4.6638x over previous
//
#include <hip/hip_runtime.h>
#include <math.h>

#define N_NODES 50000
#define P_PATHS 4
#define E_EDGES 800000
#define IN_F 256
#define OUT_F 128
#define NPB 128                        // nodes per bucket
#define NBUCK 391                      // ceil(N/NPB)
#define NCHUNK 200                     // edge chunks per path
#define CHUNK_E (E_EDGES / NCHUNK)     // 4000
#define DEG_BLOCKS 25
#define DEG_NODES 2000                 // nodes per degout block
#define GBLK 391                       // row-blocks for gemm/fc (128 rows each)

typedef unsigned short ushort_t;
typedef unsigned int uint_t;
typedef float f32x4 __attribute__((ext_vector_type(4)));
typedef short s16x8 __attribute__((ext_vector_type(8)));

__device__ __forceinline__ ushort_t f2bf(float f) {
    uint_t u = __float_as_uint(f);
    return (ushort_t)((u + 0x7FFFu + ((u >> 16) & 1u)) >> 16);   // RNE
}
__device__ __forceinline__ float bf2f(ushort_t h) {
    return __uint_as_float(((uint_t)h) << 16);
}

// ---------------- prep: W -> Wt bf16 (transposed [p][n][k]), fc_w -> bf16 ----------------
__global__ void prep_kernel(const float* __restrict__ W, const float* __restrict__ fcw,
                            ushort_t* __restrict__ Wt, ushort_t* __restrict__ fcwb)
{
    int idx = blockIdx.x * blockDim.x + threadIdx.x;
    if (idx < P_PATHS * IN_F * OUT_F) {          // 131072
        int p = idx >> 15;
        int r = idx & 32767;
        int k = r >> 7;
        int n = r & 127;
        Wt[((size_t)p << 15) + (size_t)n * IN_F + k] = f2bf(W[idx]);
    }
    if (idx < OUT_F * OUT_F) fcwb[idx] = f2bf(fcw[idx]);
}

// ---------------- deg_out via streaming LDS histogram -> rsout = rsqrt(max(deg,1)) ----------------
__global__ __launch_bounds__(256) void degout_kernel(const int* __restrict__ src,
                                                     float* __restrict__ rsout)
{
    __shared__ uint_t cnt[DEG_NODES];
    int p = blockIdx.y;
    int base = blockIdx.x * DEG_NODES;
    int t = threadIdx.x;
    for (int i = t; i < DEG_NODES; i += 256) cnt[i] = 0;
    __syncthreads();
    const int4* s4 = (const int4*)(src + (size_t)p * E_EDGES);
    for (int i = t; i < E_EDGES / 4; i += 256) {
        int4 v = s4[i];
        uint_t r;
        r = (uint_t)(v.x - base); if (r < DEG_NODES) atomicAdd(&cnt[r], 1u);
        r = (uint_t)(v.y - base); if (r < DEG_NODES) atomicAdd(&cnt[r], 1u);
        r = (uint_t)(v.z - base); if (r < DEG_NODES) atomicAdd(&cnt[r], 1u);
        r = (uint_t)(v.w - base); if (r < DEG_NODES) atomicAdd(&cnt[r], 1u);
    }
    __syncthreads();
    for (int i = t; i < DEG_NODES; i += 256) {
        uint_t c = cnt[i];
        rsout[(size_t)p * N_NODES + base + i] = rsqrtf((float)(c ? c : 1u));
    }
}

// ---------------- bucket histogram (by dst>>7), all paths ----------------
__global__ __launch_bounds__(256) void bhist_kernel(const int* __restrict__ dst,
                                                    uint_t* __restrict__ bcounts)
{
    __shared__ uint_t bh[NBUCK];
    int p = blockIdx.y;
    int t = threadIdx.x;
    for (int i = t; i < NBUCK; i += 256) bh[i] = 0;
    __syncthreads();
    const int4* d4 = (const int4*)(dst + (size_t)p * E_EDGES + (size_t)blockIdx.x * CHUNK_E);
    for (int i = t; i < CHUNK_E / 4; i += 256) {
        int4 v = d4[i];
        atomicAdd(&bh[v.x >> 7], 1u);
        atomicAdd(&bh[v.y >> 7], 1u);
        atomicAdd(&bh[v.z >> 7], 1u);
        atomicAdd(&bh[v.w >> 7], 1u);
    }
    __syncthreads();
    for (int i = t; i < NBUCK; i += 256)
        if (bh[i]) atomicAdd(&bcounts[p * NBUCK + i], bh[i]);
}

// ---------------- flat exclusive scan over P*NBUCK bucket counts ----------------
__global__ __launch_bounds__(1024) void bscan_kernel(const uint_t* __restrict__ bcounts,
                                                     int* __restrict__ bstart,
                                                     int* __restrict__ bcursor)
{
    __shared__ int a[2048], b[2048];
    int t = threadIdx.x;
    for (int i = t; i < 2048; i += 1024)
        a[i] = (i < P_PATHS * NBUCK) ? (int)bcounts[i] : 0;
    __syncthreads();
    int* pin = a; int* pout = b;
    for (int off = 1; off < 2048; off <<= 1) {
        for (int i = t; i < 2048; i += 1024)
            pout[i] = pin[i] + (i >= off ? pin[i - off] : 0);
        __syncthreads();
        int* tmp = pin; pin = pout; pout = tmp;
    }
    for (int i = t; i < P_PATHS * NBUCK; i += 1024) {
        int st = pin[i] - (int)bcounts[i];
        bstart[i] = st;
        bcursor[i] = st;
    }
    if (t == 0) bstart[P_PATHS * NBUCK] = pin[P_PATHS * NBUCK - 1];
}

// ---------------- scatter packed edges (src | dloc<<16) into bucket order (one path) ----------------
__global__ __launch_bounds__(256) void bscatter_kernel(const int* __restrict__ src,
                                                       const int* __restrict__ dst,
                                                       int* __restrict__ bcursor_p,
                                                       uint_t* __restrict__ ebuf,
                                                       int sub)   // p*E: flat->local
{
    __shared__ uint_t bh[NBUCK];
    __shared__ uint_t lbase[NBUCK];
    int t = threadIdx.x;
    for (int i = t; i < NBUCK; i += 256) bh[i] = 0;
    __syncthreads();
    size_t ebase = (size_t)blockIdx.x * CHUNK_E;
    const int4* d4 = (const int4*)(dst + ebase);
    const int4* s4 = (const int4*)(src + ebase);
    for (int i = t; i < CHUNK_E / 4; i += 256) {
        int4 v = d4[i];
        atomicAdd(&bh[v.x >> 7], 1u);
        atomicAdd(&bh[v.y >> 7], 1u);
        atomicAdd(&bh[v.z >> 7], 1u);
        atomicAdd(&bh[v.w >> 7], 1u);
    }
    __syncthreads();
    for (int i = t; i < NBUCK; i += 256) {
        uint_t c = bh[i];
        lbase[i] = c ? (uint_t)(atomicAdd(&bcursor_p[i], (int)c) - sub) : 0u;
        bh[i] = 0;     // reuse as local cursor
    }
    __syncthreads();
    for (int i = t; i < CHUNK_E / 4; i += 256) {
        int4 d = d4[i];
        int4 s = s4[i];
        { int bk = d.x >> 7; uint_t pos = lbase[bk] + atomicAdd(&bh[bk], 1u); ebuf[pos] = (uint_t)s.x | ((uint_t)(d.x & 127) << 16); }
        { int bk = d.y >> 7; uint_t pos = lbase[bk] + atomicAdd(&bh[bk], 1u); ebuf[pos] = (uint_t)s.y | ((uint_t)(d.y & 127) << 16); }
        { int bk = d.z >> 7; uint_t pos = lbase[bk] + atomicAdd(&bh[bk], 1u); ebuf[pos] = (uint_t)s.z | ((uint_t)(d.z & 127) << 16); }
        { int bk = d.w >> 7; uint_t pos = lbase[bk] + atomicAdd(&bh[bk], 1u); ebuf[pos] = (uint_t)s.w | ((uint_t)(d.w & 127) << 16); }
    }
}

// ---------------- per-bucket local CSR build: eidx2 (src, node-sorted) + rsn row offsets ----------------
__global__ __launch_bounds__(256) void blocal_kernel(const uint_t* __restrict__ ebuf,
                                                     const int* __restrict__ bstart,
                                                     ushort_t* __restrict__ eidx2,
                                                     int* __restrict__ rsn,
                                                     int pbase, int sub)
{
    __shared__ uint_t hist[NPB];
    __shared__ uint_t cur[NPB];
    __shared__ uint_t sa[NPB], sb[NPB];
    int bkt = blockIdx.x;
    int t = threadIdx.x;
    if (t < NPB) hist[t] = 0;
    __syncthreads();
    int r0 = bstart[pbase + bkt] - sub;
    int r1 = bstart[pbase + bkt + 1] - sub;
    for (int e = r0 + t; e < r1; e += 256)
        atomicAdd(&hist[ebuf[e] >> 16], 1u);
    __syncthreads();
    if (t < NPB) sa[t] = hist[t];
    __syncthreads();
    uint_t* pin = sa; uint_t* pout = sb;
    for (int off = 1; off < NPB; off <<= 1) {
        if (t < NPB) pout[t] = pin[t] + (t >= off ? pin[t - off] : 0u);
        __syncthreads();
        uint_t* tmp = pin; pin = pout; pout = tmp;
    }
    if (t < NPB) {
        uint_t ex = pin[t] - hist[t];
        int node = bkt * NPB + t;
        if (node < N_NODES) rsn[node] = r0 + (int)ex;
        cur[t] = ex;
    }
    if (bkt == NBUCK - 1 && t == 0) rsn[N_NODES] = r1;   // == E_EDGES
    __syncthreads();
    for (int e = r0 + t; e < r1; e += 256) {
        uint_t pk = ebuf[e];
        int dl = (int)(pk >> 16);
        uint_t pos = atomicAdd(&cur[dl], 1u);
        eidx2[r0 + pos] = (ushort_t)(pk & 0xFFFFu);
    }
}

// ---------------- MFMA GEMM: xwb = bf16( (x @ Wt^T) * rsout )  [M=50000,K=256,N=128] ----------------
__global__ __launch_bounds__(256) void gemm_xw_kernel(const float* __restrict__ x,
                                                      const ushort_t* __restrict__ Wt,
                                                      const float* __restrict__ rsout,
                                                      ushort_t* __restrict__ xwb)
{
    __shared__ ushort_t As[128 * 40];
    __shared__ ushort_t Bs[128 * 40];
    int m0 = blockIdx.x * 128;
    int t = threadIdx.x;
    int wid = t >> 6, lane = t & 63;
    int wr = wid >> 1, wc = wid & 1;
    f32x4 acc[4][4] = {};
    int srow = t >> 1, half = (t & 1) * 16;
    for (int k0 = 0; k0 < IN_F; k0 += 32) {
        {   // A: 128x32 fp32 -> bf16 LDS
            int gr = m0 + srow;
            uint4 w0 = make_uint4(0, 0, 0, 0), w1 = make_uint4(0, 0, 0, 0);
            if (gr < N_NODES) {
                const float* ap = x + (size_t)gr * IN_F + k0 + half;
                float4 f0 = *(const float4*)(ap + 0);
                float4 f1 = *(const float4*)(ap + 4);
                float4 f2 = *(const float4*)(ap + 8);
                float4 f3 = *(const float4*)(ap + 12);
                w0.x = (uint_t)f2bf(f0.x) | ((uint_t)f2bf(f0.y) << 16);
                w0.y = (uint_t)f2bf(f0.z) | ((uint_t)f2bf(f0.w) << 16);
                w0.z = (uint_t)f2bf(f1.x) | ((uint_t)f2bf(f1.y) << 16);
                w0.w = (uint_t)f2bf(f1.z) | ((uint_t)f2bf(f1.w) << 16);
                w1.x = (uint_t)f2bf(f2.x) | ((uint_t)f2bf(f2.y) << 16);
                w1.y = (uint_t)f2bf(f2.z) | ((uint_t)f2bf(f2.w) << 16);
                w1.z = (uint_t)f2bf(f3.x) | ((uint_t)f2bf(f3.y) << 16);
                w1.w = (uint_t)f2bf(f3.z) | ((uint_t)f2bf(f3.w) << 16);
            }
            *(uint4*)&As[srow * 40 + half]     = w0;
            *(uint4*)&As[srow * 40 + half + 8] = w1;
        }
        {   // B: Wt rows ([n][k]) bf16 direct
            const ushort_t* bp = Wt + (size_t)srow * IN_F + k0 + half;
            *(uint4*)&Bs[srow * 40 + half]     = *(const uint4*)(bp);
            *(uint4*)&Bs[srow * 40 + half + 8] = *(const uint4*)(bp + 8);
        }
        __syncthreads();
        s16x8 aF[4], bF[4];
        int kk = (lane >> 4) * 8;
#pragma unroll
        for (int m = 0; m < 4; ++m)
            aF[m] = *(const s16x8*)&As[(wr * 64 + m * 16 + (lane & 15)) * 40 + kk];
#pragma unroll
        for (int n = 0; n < 4; ++n)
            bF[n] = *(const s16x8*)&Bs[(wc * 64 + n * 16 + (lane & 15)) * 40 + kk];
#pragma unroll
        for (int m = 0; m < 4; ++m)
#pragma unroll
            for (int n = 0; n < 4; ++n)
                acc[m][n] = __builtin_amdgcn_mfma_f32_16x16x32_bf16(aF[m], bF[n], acc[m][n], 0, 0, 0);
        __syncthreads();
    }
#pragma unroll
    for (int m = 0; m < 4; ++m) {
#pragma unroll
        for (int i = 0; i < 4; ++i) {
            int row = m0 + wr * 64 + m * 16 + (lane >> 4) * 4 + i;
            if (row < N_NODES) {
                float rs = rsout[row];
#pragma unroll
                for (int n = 0; n < 4; ++n) {
                    int col = wc * 64 + n * 16 + (lane & 15);
                    xwb[(size_t)row * OUT_F + col] = f2bf(acc[m][n][i] * rs);
                }
            }
        }
    }
}

// ---------------- gather: one wave per node; lane owns 2 cols; h = agg*rsqrt(deg)+b_conv ----------------
__global__ __launch_bounds__(256) void gather_kernel(const ushort_t* __restrict__ xwb,
                                                     const ushort_t* __restrict__ eidx2,
                                                     const int* __restrict__ rsn,
                                                     const float* __restrict__ bconv,
                                                     float* __restrict__ hout)
{
    int wid = threadIdx.x >> 6, lane = threadIdx.x & 63;
    int n = blockIdx.x * 4 + wid;
    int b = rsn[n], e = rsn[n + 1];
    const uint_t* base = (const uint_t*)xwb + lane;   // u32 view: row s -> s*64 + lane
    float a0 = 0.f, a1 = 0.f;
    int i = b;
    for (; i + 3 < e; i += 4) {
        int s0 = eidx2[i], s1 = eidx2[i + 1], s2 = eidx2[i + 2], s3 = eidx2[i + 3];
        uint_t w0 = base[(size_t)s0 * 64];
        uint_t w1 = base[(size_t)s1 * 64];
        uint_t w2 = base[(size_t)s2 * 64];
        uint_t w3 = base[(size_t)s3 * 64];
        a0 += (bf2f((ushort_t)w0) + bf2f((ushort_t)w1)) + (bf2f((ushort_t)w2) + bf2f((ushort_t)w3));
        a1 += (bf2f((ushort_t)(w0 >> 16)) + bf2f((ushort_t)(w1 >> 16))) +
              (bf2f((ushort_t)(w2 >> 16)) + bf2f((ushort_t)(w3 >> 16)));
    }
    for (; i < e; ++i) {
        int s = eidx2[i];
        uint_t w = base[(size_t)s * 64];
        a0 += bf2f((ushort_t)w);
        a1 += bf2f((ushort_t)(w >> 16));
    }
    int d = e - b;
    float sc = rsqrtf((float)(d > 0 ? d : 1));
    float2 bc = *(const float2*)(bconv + 2 * lane);
    float2 r;
    r.x = fmaf(a0, sc, bc.x);
    r.y = fmaf(a1, sc, bc.y);
    *(float2*)(hout + (size_t)n * OUT_F + 2 * lane) = r;
}

// ---------------- MFMA fc + tanh + per-block column sums ----------------
__global__ __launch_bounds__(256) void fc_mfma_kernel(const float* __restrict__ h,
                                                      const ushort_t* __restrict__ fcwb,
                                                      const float* __restrict__ fcb,
                                                      float* __restrict__ partial)
{
    __shared__ ushort_t As[128 * 40];
    __shared__ ushort_t Bs[128 * 40];
    __shared__ float red[2][128];
    int m0 = blockIdx.x * 128;
    int t = threadIdx.x;
    int wid = t >> 6, lane = t & 63;
    int wr = wid >> 1, wc = wid & 1;
    f32x4 acc[4][4] = {};
    int srow = t >> 1, half = (t & 1) * 16;
    for (int k0 = 0; k0 < OUT_F; k0 += 32) {
        {
            int gr = m0 + srow;
            uint4 w0 = make_uint4(0, 0, 0, 0), w1 = make_uint4(0, 0, 0, 0);
            if (gr < N_NODES) {
                const float* ap = h + (size_t)gr * OUT_F + k0 + half;
                float4 f0 = *(const float4*)(ap + 0);
                float4 f1 = *(const float4*)(ap + 4);
                float4 f2 = *(const float4*)(ap + 8);
                float4 f3 = *(const float4*)(ap + 12);
                w0.x = (uint_t)f2bf(f0.x) | ((uint_t)f2bf(f0.y) << 16);
                w0.y = (uint_t)f2bf(f0.z) | ((uint_t)f2bf(f0.w) << 16);
                w0.z = (uint_t)f2bf(f1.x) | ((uint_t)f2bf(f1.y) << 16);
                w0.w = (uint_t)f2bf(f1.z) | ((uint_t)f2bf(f1.w) << 16);
                w1.x = (uint_t)f2bf(f2.x) | ((uint_t)f2bf(f2.y) << 16);
                w1.y = (uint_t)f2bf(f2.z) | ((uint_t)f2bf(f2.w) << 16);
                w1.z = (uint_t)f2bf(f3.x) | ((uint_t)f2bf(f3.y) << 16);
                w1.w = (uint_t)f2bf(f3.z) | ((uint_t)f2bf(f3.w) << 16);
            }
            *(uint4*)&As[srow * 40 + half]     = w0;
            *(uint4*)&As[srow * 40 + half + 8] = w1;
        }
        {   // fcw[o][k] row-major is already [n][k]
            const ushort_t* bp = fcwb + (size_t)srow * OUT_F + k0 + half;
            *(uint4*)&Bs[srow * 40 + half]     = *(const uint4*)(bp);
            *(uint4*)&Bs[srow * 40 + half + 8] = *(const uint4*)(bp + 8);
        }
        __syncthreads();
        s16x8 aF[4], bF[4];
        int kk = (lane >> 4) * 8;
#pragma unroll
        for (int m = 0; m < 4; ++m)
            aF[m] = *(const s16x8*)&As[(wr * 64 + m * 16 + (lane & 15)) * 40 + kk];
#pragma unroll
        for (int n = 0; n < 4; ++n)
            bF[n] = *(const s16x8*)&Bs[(wc * 64 + n * 16 + (lane & 15)) * 40 + kk];
#pragma unroll
        for (int m = 0; m < 4; ++m)
#pragma unroll
            for (int n = 0; n < 4; ++n)
                acc[m][n] = __builtin_amdgcn_mfma_f32_16x16x32_bf16(aF[m], bF[n], acc[m][n], 0, 0, 0);
        __syncthreads();
    }
#pragma unroll
    for (int n = 0; n < 4; ++n) {
        int col = wc * 64 + n * 16 + (lane & 15);
        float fb = fcb[col];
        float s = 0.f;
#pragma unroll
        for (int m = 0; m < 4; ++m)
#pragma unroll
            for (int i = 0; i < 4; ++i) {
                int row = m0 + wr * 64 + m * 16 + (lane >> 4) * 4 + i;
                if (row < N_NODES) s += tanhf(acc[m][n][i] + fb);
            }
        s += __shfl_xor(s, 16);
        s += __shfl_xor(s, 32);
        if (lane < 16) red[wr][col] = s;
    }
    __syncthreads();
    if (t < 128)
        partial[(size_t)blockIdx.x * OUT_F + t] = red[0][t] + red[1][t];
}

// ---------------- reduce partials -> sp -> beta softmax ----------------
__global__ __launch_bounds__(512) void beta_reduce_kernel(const float* __restrict__ partial,
                                                          const float* __restrict__ att,
                                                          float* __restrict__ beta)
{
    int t = threadIdx.x;          // 512 = P*128
    int p = t >> 7, c = t & 127;
    float s = 0.f;
    for (int i = 0; i < GBLK; ++i)
        s += partial[((size_t)p * GBLK + i) * OUT_F + c];
    float v = att[p * OUT_F + c] * (s * (1.0f / N_NODES));
    __shared__ float red[512];
    red[t] = v;
    __syncthreads();
    for (int off = 64; off >= 1; off >>= 1) {
        if (c < off) red[t] += red[t + off];
        __syncthreads();
    }
    if (t == 0) {
        float w[P_PATHS], mx = -1e30f;
        for (int q = 0; q < P_PATHS; ++q) { w[q] = red[q * 128]; mx = fmaxf(mx, w[q]); }
        float sum = 0.f;
        for (int q = 0; q < P_PATHS; ++q) { w[q] = expf(w[q] - mx); sum += w[q]; }
        for (int q = 0; q < P_PATHS; ++q) beta[q] = w[q] / sum;
    }
}

// ---------------- out = sum_p beta[p]*h[p] + h_bias ----------------
__global__ void combine_kernel(const float* __restrict__ h, const float* __restrict__ hbias,
                               const float* __restrict__ beta, float* __restrict__ out)
{
    int idx = blockIdx.x * blockDim.x + threadIdx.x;
    if (idx >= N_NODES * (OUT_F / 4)) return;
    int n = idx >> 5;
    int j4 = (idx & 31) * 4;
    float4 hb = *(const float4*)(hbias + j4);
    float4 r = hb;
#pragma unroll
    for (int p = 0; p < P_PATHS; ++p) {
        float bp = beta[p];
        float4 a = *(const float4*)(h + ((size_t)p * N_NODES + n) * OUT_F + j4);
        r.x = fmaf(bp, a.x, r.x); r.y = fmaf(bp, a.y, r.y);
        r.z = fmaf(bp, a.z, r.z); r.w = fmaf(bp, a.w, r.w);
    }
    *(float4*)(out + (size_t)idx * 4) = r;
}

extern "C" void kernel_launch(void* const* d_in, const int* in_sizes, int n_in,
                              void* d_out, int out_size, void* d_ws, size_t ws_size,
                              hipStream_t stream)
{
    const float* x      = (const float*)d_in[0];
    const float* W      = (const float*)d_in[1];
    const float* b_conv = (const float*)d_in[2];
    const float* att    = (const float*)d_in[3];
    const float* fc_w   = (const float*)d_in[4];
    const float* fc_b   = (const float*)d_in[5];
    const float* h_bias = (const float*)d_in[6];
    const int*   src    = (const int*)d_in[7];
    const int*   dst    = (const int*)d_in[8];
    float* out = (float*)d_out;
    float* ws  = (float*)d_ws;

    // ---- ws layout (float units), total ~122 MB ----
    size_t off_h       = 0;                                           // P*N*128
    size_t off_rsout   = off_h + (size_t)P_PATHS * N_NODES * OUT_F;   // P*N
    size_t off_partial = off_rsout + (size_t)P_PATHS * N_NODES;       // P*GBLK*128
    size_t off_beta    = off_partial + (size_t)P_PATHS * GBLK * OUT_F;
    size_t off_i32     = (off_beta + 4 + 63) & ~(size_t)63;
    // int region (units of int)
    size_t i_bstart  = 0;                                  // P*NBUCK+1 -> pad 1600
    size_t i_bcursor = 1600;                               // P*NBUCK   -> pad 3200
    size_t i_bcounts = 3200;                               // P*NBUCK   -> pad 4800
    size_t i_rsn     = 4800;                               // N+1 -> pad 54848
    size_t i_ebuf    = 54848;                              // E (single path, reused)
    size_t n_ints    = i_ebuf + (size_t)E_EDGES;
    size_t off_u16   = off_i32 + ((n_ints + 63) & ~(size_t)63);
    // ushort region (units of ushort)
    size_t u_xwb   = 0;                                    // N*128 (single path, reused)
    size_t u_eidx2 = u_xwb + (size_t)N_NODES * OUT_F;      // E (single path, reused)
    size_t u_Wt    = u_eidx2 + (size_t)E_EDGES;            // P*IN*OUT
    size_t u_fcwb  = u_Wt + (size_t)P_PATHS * IN_F * OUT_F;

    float* h       = ws + off_h;
    float* rsout   = ws + off_rsout;
    float* partial = ws + off_partial;
    float* beta    = ws + off_beta;
    int*   ibase   = (int*)(ws + off_i32);
    int*    bstart  = ibase + i_bstart;
    int*    bcursor = ibase + i_bcursor;
    uint_t* bcounts = (uint_t*)(ibase + i_bcounts);
    int*    rsn     = ibase + i_rsn;
    uint_t* ebuf    = (uint_t*)(ibase + i_ebuf);
    ushort_t* ubase = (ushort_t*)(ws + off_u16);
    ushort_t* xwb   = ubase + u_xwb;
    ushort_t* eidx2 = ubase + u_eidx2;
    ushort_t* Wt    = ubase + u_Wt;
    ushort_t* fcwb  = ubase + u_fcwb;

    // only bucket counters accumulate -> zero each call
    hipMemsetAsync(bcounts, 0, (size_t)P_PATHS * NBUCK * sizeof(uint_t), stream);

    prep_kernel<<<(P_PATHS * IN_F * OUT_F + 255) / 256, 256, 0, stream>>>(W, fc_w, Wt, fcwb);
    degout_kernel<<<dim3(DEG_BLOCKS, P_PATHS), 256, 0, stream>>>(src, rsout);
    bhist_kernel<<<dim3(NCHUNK, P_PATHS), 256, 0, stream>>>(dst, bcounts);
    bscan_kernel<<<1, 1024, 0, stream>>>(bcounts, bstart, bcursor);

    for (int p = 0; p < P_PATHS; ++p) {
        int sub = p * E_EDGES;
        gemm_xw_kernel<<<GBLK, 256, 0, stream>>>(
            x, Wt + ((size_t)p << 15), rsout + (size_t)p * N_NODES, xwb);
        bscatter_kernel<<<NCHUNK, 256, 0, stream>>>(
            src + (size_t)p * E_EDGES, dst + (size_t)p * E_EDGES,
            bcursor + (size_t)p * NBUCK, ebuf, sub);
        blocal_kernel<<<NBUCK, 256, 0, stream>>>(
            ebuf, bstart, eidx2, rsn, p * NBUCK, sub);
        gather_kernel<<<N_NODES / 4, 256, 0, stream>>>(
            xwb, eidx2, rsn, b_conv + p * OUT_F, h + (size_t)p * N_NODES * OUT_F);
        fc_mfma_kernel<<<GBLK, 256, 0, stream>>>(
            h + (size_t)p * N_NODES * OUT_F, fcwb, fc_b,
            partial + (size_t)p * GBLK * OUT_F);
    }
    beta_reduce_kernel<<<1, 512, 0, stream>>>(partial, att, beta);
    combine_kernel<<<(N_NODES * (OUT_F / 4) + 255) / 256, 256, 0, stream>>>(
        h, h_bias, beta, out);
}

// Round 5
// 473.127 us; speedup vs baseline: 6.9324x; 1.4864x over previous
//
#include <hip/hip_runtime.h>
#include <math.h>

#define N_NODES 50000
#define P_PATHS 4
#define E_EDGES 800000
#define IN_F 256
#define OUT_F 128
#define NPB 128                        // nodes per bucket
#define NBUCK 391                      // ceil(N/NPB)
#define NCHUNK 200                     // edge chunks per path
#define CHUNK_E (E_EDGES / NCHUNK)     // 4000
#define GBLK 391                       // row-blocks for gemm/fc (128 rows each)
#define DSL 8                          // edge slices for deg-out histogram
#define HALF_N 25000                   // nodes per half
#define HALF_W 12500                   // packed u32 words per half

typedef unsigned short ushort_t;
typedef unsigned int uint_t;
typedef float f32x4 __attribute__((ext_vector_type(4)));
typedef short s16x8 __attribute__((ext_vector_type(8)));

__device__ __forceinline__ ushort_t f2bf(float f) {
    uint_t u = __float_as_uint(f);
    return (ushort_t)((u + 0x7FFFu + ((u >> 16) & 1u)) >> 16);   // RNE
}
__device__ __forceinline__ float bf2f(ushort_t h) {
    return __uint_as_float(((uint_t)h) << 16);
}

// ---------------- prep: W -> Wt bf16 (transposed [p][n][k]), fc_w -> bf16 ----------------
__global__ void prep_kernel(const float* __restrict__ W, const float* __restrict__ fcw,
                            ushort_t* __restrict__ Wt, ushort_t* __restrict__ fcwb)
{
    int idx = blockIdx.x * blockDim.x + threadIdx.x;
    if (idx < P_PATHS * IN_F * OUT_F) {          // 131072
        int p = idx >> 15;
        int r = idx & 32767;
        int k = r >> 7;
        int n = r & 127;
        Wt[((size_t)p << 15) + (size_t)n * IN_F + k] = f2bf(W[idx]);
    }
    if (idx < OUT_F * OUT_F) fcwb[idx] = f2bf(fcw[idx]);
}

// ---------------- deg_out: sliced LDS histograms (packed 2×u16 per u32) ----------------
__global__ __launch_bounds__(256) void deghist_kernel(const int* __restrict__ src,
                                                      uint_t* __restrict__ dhist)
{
    __shared__ uint_t cnt[HALF_W];   // 50 KB
    int sl = blockIdx.x, hf = blockIdx.y, p = blockIdx.z;
    int t = threadIdx.x;
    int nbase = hf * HALF_N;
    for (int i = t; i < HALF_W; i += 256) cnt[i] = 0;
    __syncthreads();
    const int4* s4 = (const int4*)(src + (size_t)p * E_EDGES + (size_t)sl * (E_EDGES / DSL));
    for (int i = t; i < E_EDGES / DSL / 4; i += 256) {
        int4 v = s4[i];
        uint_t r;
        r = (uint_t)(v.x - nbase); if (r < HALF_N) atomicAdd(&cnt[r >> 1], 1u << ((r & 1) * 16));
        r = (uint_t)(v.y - nbase); if (r < HALF_N) atomicAdd(&cnt[r >> 1], 1u << ((r & 1) * 16));
        r = (uint_t)(v.z - nbase); if (r < HALF_N) atomicAdd(&cnt[r >> 1], 1u << ((r & 1) * 16));
        r = (uint_t)(v.w - nbase); if (r < HALF_N) atomicAdd(&cnt[r >> 1], 1u << ((r & 1) * 16));
    }
    __syncthreads();
    uint_t* outp = dhist + (((size_t)p * 2 + hf) * DSL + sl) * HALF_W;
    for (int i = t; i < HALF_W; i += 256) outp[i] = cnt[i];
}

// ---------------- merge slices -> rsout = rsqrt(max(deg_out,1)) ----------------
__global__ void rsout_kernel(const uint_t* __restrict__ dhist, float* __restrict__ rsout)
{
    int idx = blockIdx.x * 256 + threadIdx.x;      // over P*2*HALF_W
    if (idx >= P_PATHS * 2 * HALF_W) return;
    int ph = idx / HALF_W;
    int w  = idx % HALF_W;
    const uint_t* base = dhist + (size_t)ph * DSL * HALF_W + w;
    uint_t s = 0;
#pragma unroll
    for (int sl = 0; sl < DSL; ++sl) s += base[(size_t)sl * HALF_W];
    int p = ph >> 1, hf = ph & 1;
    int node = hf * HALF_N + 2 * w;
    uint_t c0 = s & 0xFFFFu, c1 = s >> 16;
    rsout[(size_t)p * N_NODES + node]     = rsqrtf((float)(c0 ? c0 : 1u));
    rsout[(size_t)p * N_NODES + node + 1] = rsqrtf((float)(c1 ? c1 : 1u));
}

// ---------------- bucket histogram (by dst>>7), all paths ----------------
__global__ __launch_bounds__(256) void bhist_kernel(const int* __restrict__ dst,
                                                    uint_t* __restrict__ bcounts)
{
    __shared__ uint_t bh[NBUCK];
    int p = blockIdx.y;
    int t = threadIdx.x;
    for (int i = t; i < NBUCK; i += 256) bh[i] = 0;
    __syncthreads();
    const int4* d4 = (const int4*)(dst + (size_t)p * E_EDGES + (size_t)blockIdx.x * CHUNK_E);
    for (int i = t; i < CHUNK_E / 4; i += 256) {
        int4 v = d4[i];
        atomicAdd(&bh[v.x >> 7], 1u);
        atomicAdd(&bh[v.y >> 7], 1u);
        atomicAdd(&bh[v.z >> 7], 1u);
        atomicAdd(&bh[v.w >> 7], 1u);
    }
    __syncthreads();
    for (int i = t; i < NBUCK; i += 256)
        if (bh[i]) atomicAdd(&bcounts[p * NBUCK + i], bh[i]);
}

// ---------------- flat exclusive scan over P*NBUCK bucket counts ----------------
__global__ __launch_bounds__(1024) void bscan_kernel(const uint_t* __restrict__ bcounts,
                                                     int* __restrict__ bstart,
                                                     int* __restrict__ bcursor)
{
    __shared__ int a[2048], b[2048];
    int t = threadIdx.x;
    for (int i = t; i < 2048; i += 1024)
        a[i] = (i < P_PATHS * NBUCK) ? (int)bcounts[i] : 0;
    __syncthreads();
    int* pin = a; int* pout = b;
    for (int off = 1; off < 2048; off <<= 1) {
        for (int i = t; i < 2048; i += 1024)
            pout[i] = pin[i] + (i >= off ? pin[i - off] : 0);
        __syncthreads();
        int* tmp = pin; pin = pout; pout = tmp;
    }
    for (int i = t; i < P_PATHS * NBUCK; i += 1024) {
        int st = pin[i] - (int)bcounts[i];
        bstart[i] = st;
        bcursor[i] = st;
    }
    if (t == 0) bstart[P_PATHS * NBUCK] = pin[P_PATHS * NBUCK - 1];
}

// ---------------- scatter packed edges (src | dloc<<16) into bucket order (one path) ----------------
__global__ __launch_bounds__(256) void bscatter_kernel(const int* __restrict__ src,
                                                       const int* __restrict__ dst,
                                                       int* __restrict__ bcursor_p,
                                                       uint_t* __restrict__ ebuf,
                                                       int sub)   // p*E: flat->local
{
    __shared__ uint_t bh[NBUCK];
    __shared__ uint_t lbase[NBUCK];
    int t = threadIdx.x;
    for (int i = t; i < NBUCK; i += 256) bh[i] = 0;
    __syncthreads();
    size_t ebase = (size_t)blockIdx.x * CHUNK_E;
    const int4* d4 = (const int4*)(dst + ebase);
    const int4* s4 = (const int4*)(src + ebase);
    for (int i = t; i < CHUNK_E / 4; i += 256) {
        int4 v = d4[i];
        atomicAdd(&bh[v.x >> 7], 1u);
        atomicAdd(&bh[v.y >> 7], 1u);
        atomicAdd(&bh[v.z >> 7], 1u);
        atomicAdd(&bh[v.w >> 7], 1u);
    }
    __syncthreads();
    for (int i = t; i < NBUCK; i += 256) {
        uint_t c = bh[i];
        lbase[i] = c ? (uint_t)(atomicAdd(&bcursor_p[i], (int)c) - sub) : 0u;
        bh[i] = 0;     // reuse as local cursor
    }
    __syncthreads();
    for (int i = t; i < CHUNK_E / 4; i += 256) {
        int4 d = d4[i];
        int4 s = s4[i];
        { int bk = d.x >> 7; uint_t pos = lbase[bk] + atomicAdd(&bh[bk], 1u); ebuf[pos] = (uint_t)s.x | ((uint_t)(d.x & 127) << 16); }
        { int bk = d.y >> 7; uint_t pos = lbase[bk] + atomicAdd(&bh[bk], 1u); ebuf[pos] = (uint_t)s.y | ((uint_t)(d.y & 127) << 16); }
        { int bk = d.z >> 7; uint_t pos = lbase[bk] + atomicAdd(&bh[bk], 1u); ebuf[pos] = (uint_t)s.z | ((uint_t)(d.z & 127) << 16); }
        { int bk = d.w >> 7; uint_t pos = lbase[bk] + atomicAdd(&bh[bk], 1u); ebuf[pos] = (uint_t)s.w | ((uint_t)(d.w & 127) << 16); }
    }
}

// ---------------- per-bucket local CSR build: eidx2 (src, node-sorted) + rsn row offsets ----------------
__global__ __launch_bounds__(256) void blocal_kernel(const uint_t* __restrict__ ebuf,
                                                     const int* __restrict__ bstart,
                                                     ushort_t* __restrict__ eidx2,
                                                     int* __restrict__ rsn,
                                                     int pbase, int sub)
{
    __shared__ uint_t hist[NPB];
    __shared__ uint_t cur[NPB];
    __shared__ uint_t sa[NPB], sb[NPB];
    int bkt = blockIdx.x;
    int t = threadIdx.x;
    if (t < NPB) hist[t] = 0;
    __syncthreads();
    int r0 = bstart[pbase + bkt] - sub;
    int r1 = bstart[pbase + bkt + 1] - sub;
    for (int e = r0 + t; e < r1; e += 256)
        atomicAdd(&hist[ebuf[e] >> 16], 1u);
    __syncthreads();
    if (t < NPB) sa[t] = hist[t];
    __syncthreads();
    uint_t* pin = sa; uint_t* pout = sb;
    for (int off = 1; off < NPB; off <<= 1) {
        if (t < NPB) pout[t] = pin[t] + (t >= off ? pin[t - off] : 0u);
        __syncthreads();
        uint_t* tmp = pin; pin = pout; pout = tmp;
    }
    if (t < NPB) {
        uint_t ex = pin[t] - hist[t];
        int node = bkt * NPB + t;
        if (node < N_NODES) rsn[node] = r0 + (int)ex;
        cur[t] = ex;
    }
    if (bkt == NBUCK - 1 && t == 0) rsn[N_NODES] = r1;   // == E_EDGES
    __syncthreads();
    for (int e = r0 + t; e < r1; e += 256) {
        uint_t pk = ebuf[e];
        int dl = (int)(pk >> 16);
        uint_t pos = atomicAdd(&cur[dl], 1u);
        eidx2[r0 + pos] = (ushort_t)(pk & 0xFFFFu);
    }
}

// ---------------- MFMA GEMM: xwb = bf16( (x @ Wt^T) * rsout )  [M=50000,K=256,N=128] ----------------
__global__ __launch_bounds__(256) void gemm_xw_kernel(const float* __restrict__ x,
                                                      const ushort_t* __restrict__ Wt,
                                                      const float* __restrict__ rsout,
                                                      ushort_t* __restrict__ xwb)
{
    __shared__ ushort_t As[128 * 40];
    __shared__ ushort_t Bs[128 * 40];
    int m0 = blockIdx.x * 128;
    int t = threadIdx.x;
    int wid = t >> 6, lane = t & 63;
    int wr = wid >> 1, wc = wid & 1;
    f32x4 acc[4][4] = {};
    int srow = t >> 1, half = (t & 1) * 16;
    for (int k0 = 0; k0 < IN_F; k0 += 32) {
        {   // A: 128x32 fp32 -> bf16 LDS
            int gr = m0 + srow;
            uint4 w0 = make_uint4(0, 0, 0, 0), w1 = make_uint4(0, 0, 0, 0);
            if (gr < N_NODES) {
                const float* ap = x + (size_t)gr * IN_F + k0 + half;
                float4 f0 = *(const float4*)(ap + 0);
                float4 f1 = *(const float4*)(ap + 4);
                float4 f2 = *(const float4*)(ap + 8);
                float4 f3 = *(const float4*)(ap + 12);
                w0.x = (uint_t)f2bf(f0.x) | ((uint_t)f2bf(f0.y) << 16);
                w0.y = (uint_t)f2bf(f0.z) | ((uint_t)f2bf(f0.w) << 16);
                w0.z = (uint_t)f2bf(f1.x) | ((uint_t)f2bf(f1.y) << 16);
                w0.w = (uint_t)f2bf(f1.z) | ((uint_t)f2bf(f1.w) << 16);
                w1.x = (uint_t)f2bf(f2.x) | ((uint_t)f2bf(f2.y) << 16);
                w1.y = (uint_t)f2bf(f2.z) | ((uint_t)f2bf(f2.w) << 16);
                w1.z = (uint_t)f2bf(f3.x) | ((uint_t)f2bf(f3.y) << 16);
                w1.w = (uint_t)f2bf(f3.z) | ((uint_t)f2bf(f3.w) << 16);
            }
            *(uint4*)&As[srow * 40 + half]     = w0;
            *(uint4*)&As[srow * 40 + half + 8] = w1;
        }
        {   // B: Wt rows ([n][k]) bf16 direct
            const ushort_t* bp = Wt + (size_t)srow * IN_F + k0 + half;
            *(uint4*)&Bs[srow * 40 + half]     = *(const uint4*)(bp);
            *(uint4*)&Bs[srow * 40 + half + 8] = *(const uint4*)(bp + 8);
        }
        __syncthreads();
        s16x8 aF[4], bF[4];
        int kk = (lane >> 4) * 8;
#pragma unroll
        for (int m = 0; m < 4; ++m)
            aF[m] = *(const s16x8*)&As[(wr * 64 + m * 16 + (lane & 15)) * 40 + kk];
#pragma unroll
        for (int n = 0; n < 4; ++n)
            bF[n] = *(const s16x8*)&Bs[(wc * 64 + n * 16 + (lane & 15)) * 40 + kk];
#pragma unroll
        for (int m = 0; m < 4; ++m)
#pragma unroll
            for (int n = 0; n < 4; ++n)
                acc[m][n] = __builtin_amdgcn_mfma_f32_16x16x32_bf16(aF[m], bF[n], acc[m][n], 0, 0, 0);
        __syncthreads();
    }
#pragma unroll
    for (int m = 0; m < 4; ++m) {
#pragma unroll
        for (int i = 0; i < 4; ++i) {
            int row = m0 + wr * 64 + m * 16 + (lane >> 4) * 4 + i;
            if (row < N_NODES) {
                float rs = rsout[row];
#pragma unroll
                for (int n = 0; n < 4; ++n) {
                    int col = wc * 64 + n * 16 + (lane & 15);
                    xwb[(size_t)row * OUT_F + col] = f2bf(acc[m][n][i] * rs);
                }
            }
        }
    }
}

// ---------------- gather: one wave per node; lane owns 2 cols; h = agg*rsqrt(deg)+b_conv ----------------
__global__ __launch_bounds__(256) void gather_kernel(const ushort_t* __restrict__ xwb,
                                                     const ushort_t* __restrict__ eidx2,
                                                     const int* __restrict__ rsn,
                                                     const float* __restrict__ bconv,
                                                     float* __restrict__ hout)
{
    int wid = threadIdx.x >> 6, lane = threadIdx.x & 63;
    int n = blockIdx.x * 4 + wid;
    int b = rsn[n], e = rsn[n + 1];
    const uint_t* base = (const uint_t*)xwb + lane;   // u32 view: row s -> s*64 + lane
    float a0 = 0.f, a1 = 0.f;
    int i = b;
    for (; i + 3 < e; i += 4) {
        int s0 = eidx2[i], s1 = eidx2[i + 1], s2 = eidx2[i + 2], s3 = eidx2[i + 3];
        uint_t w0 = base[(size_t)s0 * 64];
        uint_t w1 = base[(size_t)s1 * 64];
        uint_t w2 = base[(size_t)s2 * 64];
        uint_t w3 = base[(size_t)s3 * 64];
        a0 += (bf2f((ushort_t)w0) + bf2f((ushort_t)w1)) + (bf2f((ushort_t)w2) + bf2f((ushort_t)w3));
        a1 += (bf2f((ushort_t)(w0 >> 16)) + bf2f((ushort_t)(w1 >> 16))) +
              (bf2f((ushort_t)(w2 >> 16)) + bf2f((ushort_t)(w3 >> 16)));
    }
    for (; i < e; ++i) {
        int s = eidx2[i];
        uint_t w = base[(size_t)s * 64];
        a0 += bf2f((ushort_t)w);
        a1 += bf2f((ushort_t)(w >> 16));
    }
    int d = e - b;
    float sc = rsqrtf((float)(d > 0 ? d : 1));
    float2 bc = *(const float2*)(bconv + 2 * lane);
    float2 r;
    r.x = fmaf(a0, sc, bc.x);
    r.y = fmaf(a1, sc, bc.y);
    *(float2*)(hout + (size_t)n * OUT_F + 2 * lane) = r;
}

// ---------------- MFMA fc + tanh + per-block column sums ----------------
__global__ __launch_bounds__(256) void fc_mfma_kernel(const float* __restrict__ h,
                                                      const ushort_t* __restrict__ fcwb,
                                                      const float* __restrict__ fcb,
                                                      float* __restrict__ partial)
{
    __shared__ ushort_t As[128 * 40];
    __shared__ ushort_t Bs[128 * 40];
    __shared__ float red[2][128];
    int m0 = blockIdx.x * 128;
    int t = threadIdx.x;
    int wid = t >> 6, lane = t & 63;
    int wr = wid >> 1, wc = wid & 1;
    f32x4 acc[4][4] = {};
    int srow = t >> 1, half = (t & 1) * 16;
    for (int k0 = 0; k0 < OUT_F; k0 += 32) {
        {
            int gr = m0 + srow;
            uint4 w0 = make_uint4(0, 0, 0, 0), w1 = make_uint4(0, 0, 0, 0);
            if (gr < N_NODES) {
                const float* ap = h + (size_t)gr * OUT_F + k0 + half;
                float4 f0 = *(const float4*)(ap + 0);
                float4 f1 = *(const float4*)(ap + 4);
                float4 f2 = *(const float4*)(ap + 8);
                float4 f3 = *(const float4*)(ap + 12);
                w0.x = (uint_t)f2bf(f0.x) | ((uint_t)f2bf(f0.y) << 16);
                w0.y = (uint_t)f2bf(f0.z) | ((uint_t)f2bf(f0.w) << 16);
                w0.z = (uint_t)f2bf(f1.x) | ((uint_t)f2bf(f1.y) << 16);
                w0.w = (uint_t)f2bf(f1.z) | ((uint_t)f2bf(f1.w) << 16);
                w1.x = (uint_t)f2bf(f2.x) | ((uint_t)f2bf(f2.y) << 16);
                w1.y = (uint_t)f2bf(f2.z) | ((uint_t)f2bf(f2.w) << 16);
                w1.z = (uint_t)f2bf(f3.x) | ((uint_t)f2bf(f3.y) << 16);
                w1.w = (uint_t)f2bf(f3.z) | ((uint_t)f2bf(f3.w) << 16);
            }
            *(uint4*)&As[srow * 40 + half]     = w0;
            *(uint4*)&As[srow * 40 + half + 8] = w1;
        }
        {   // fcw[o][k] row-major is already [n][k]
            const ushort_t* bp = fcwb + (size_t)srow * OUT_F + k0 + half;
            *(uint4*)&Bs[srow * 40 + half]     = *(const uint4*)(bp);
            *(uint4*)&Bs[srow * 40 + half + 8] = *(const uint4*)(bp + 8);
        }
        __syncthreads();
        s16x8 aF[4], bF[4];
        int kk = (lane >> 4) * 8;
#pragma unroll
        for (int m = 0; m < 4; ++m)
            aF[m] = *(const s16x8*)&As[(wr * 64 + m * 16 + (lane & 15)) * 40 + kk];
#pragma unroll
        for (int n = 0; n < 4; ++n)
            bF[n] = *(const s16x8*)&Bs[(wc * 64 + n * 16 + (lane & 15)) * 40 + kk];
#pragma unroll
        for (int m = 0; m < 4; ++m)
#pragma unroll
            for (int n = 0; n < 4; ++n)
                acc[m][n] = __builtin_amdgcn_mfma_f32_16x16x32_bf16(aF[m], bF[n], acc[m][n], 0, 0, 0);
        __syncthreads();
    }
#pragma unroll
    for (int n = 0; n < 4; ++n) {
        int col = wc * 64 + n * 16 + (lane & 15);
        float fb = fcb[col];
        float s = 0.f;
#pragma unroll
        for (int m = 0; m < 4; ++m)
#pragma unroll
            for (int i = 0; i < 4; ++i) {
                int row = m0 + wr * 64 + m * 16 + (lane >> 4) * 4 + i;
                if (row < N_NODES) s += tanhf(acc[m][n][i] + fb);
            }
        s += __shfl_xor(s, 16);
        s += __shfl_xor(s, 32);
        if (lane < 16) red[wr][col] = s;
    }
    __syncthreads();
    if (t < 128)
        partial[(size_t)blockIdx.x * OUT_F + t] = red[0][t] + red[1][t];
}

// ---------------- reduce partials -> sp -> beta softmax ----------------
__global__ __launch_bounds__(512) void beta_reduce_kernel(const float* __restrict__ partial,
                                                          const float* __restrict__ att,
                                                          float* __restrict__ beta)
{
    int t = threadIdx.x;          // 512 = P*128
    int p = t >> 7, c = t & 127;
    float s = 0.f;
    for (int i = 0; i < GBLK; ++i)
        s += partial[((size_t)p * GBLK + i) * OUT_F + c];
    float v = att[p * OUT_F + c] * (s * (1.0f / N_NODES));
    __shared__ float red[512];
    red[t] = v;
    __syncthreads();
    for (int off = 64; off >= 1; off >>= 1) {
        if (c < off) red[t] += red[t + off];
        __syncthreads();
    }
    if (t == 0) {
        float w[P_PATHS], mx = -1e30f;
        for (int q = 0; q < P_PATHS; ++q) { w[q] = red[q * 128]; mx = fmaxf(mx, w[q]); }
        float sum = 0.f;
        for (int q = 0; q < P_PATHS; ++q) { w[q] = expf(w[q] - mx); sum += w[q]; }
        for (int q = 0; q < P_PATHS; ++q) beta[q] = w[q] / sum;
    }
}

// ---------------- out = sum_p beta[p]*h[p] + h_bias ----------------
__global__ void combine_kernel(const float* __restrict__ h, const float* __restrict__ hbias,
                               const float* __restrict__ beta, float* __restrict__ out)
{
    int idx = blockIdx.x * blockDim.x + threadIdx.x;
    if (idx >= N_NODES * (OUT_F / 4)) return;
    int n = idx >> 5;
    int j4 = (idx & 31) * 4;
    float4 hb = *(const float4*)(hbias + j4);
    float4 r = hb;
#pragma unroll
    for (int p = 0; p < P_PATHS; ++p) {
        float bp = beta[p];
        float4 a = *(const float4*)(h + ((size_t)p * N_NODES + n) * OUT_F + j4);
        r.x = fmaf(bp, a.x, r.x); r.y = fmaf(bp, a.y, r.y);
        r.z = fmaf(bp, a.z, r.z); r.w = fmaf(bp, a.w, r.w);
    }
    *(float4*)(out + (size_t)idx * 4) = r;
}

extern "C" void kernel_launch(void* const* d_in, const int* in_sizes, int n_in,
                              void* d_out, int out_size, void* d_ws, size_t ws_size,
                              hipStream_t stream)
{
    const float* x      = (const float*)d_in[0];
    const float* W      = (const float*)d_in[1];
    const float* b_conv = (const float*)d_in[2];
    const float* att    = (const float*)d_in[3];
    const float* fc_w   = (const float*)d_in[4];
    const float* fc_b   = (const float*)d_in[5];
    const float* h_bias = (const float*)d_in[6];
    const int*   src    = (const int*)d_in[7];
    const int*   dst    = (const int*)d_in[8];
    float* out = (float*)d_out;
    float* ws  = (float*)d_ws;

    // ---- ws layout (float units), total ~126 MB ----
    size_t off_h       = 0;                                           // P*N*128
    size_t off_rsout   = off_h + (size_t)P_PATHS * N_NODES * OUT_F;   // P*N
    size_t off_partial = off_rsout + (size_t)P_PATHS * N_NODES;       // P*GBLK*128
    size_t off_beta    = off_partial + (size_t)P_PATHS * GBLK * OUT_F;
    size_t off_i32     = (off_beta + 4 + 63) & ~(size_t)63;
    // int region (units of int)
    size_t i_bstart  = 0;                                  // P*NBUCK+1 -> pad 1600
    size_t i_bcursor = 1600;                               // P*NBUCK   -> pad 3200
    size_t i_bcounts = 3200;                               // P*NBUCK   -> pad 4800
    size_t i_rsn     = 4800;                               // N+1 -> pad 54848
    size_t i_dhist   = 54848;                              // P*2*DSL*HALF_W = 800000
    size_t i_ebuf    = i_dhist + (size_t)P_PATHS * 2 * DSL * HALF_W;  // E (single path, reused)
    size_t n_ints    = i_ebuf + (size_t)E_EDGES;
    size_t off_u16   = off_i32 + ((n_ints + 63) & ~(size_t)63);
    // ushort region (units of ushort)
    size_t u_xwb   = 0;                                    // N*128 (single path, reused)
    size_t u_eidx2 = u_xwb + (size_t)N_NODES * OUT_F;      // E (single path, reused)
    size_t u_Wt    = u_eidx2 + (size_t)E_EDGES;            // P*IN*OUT
    size_t u_fcwb  = u_Wt + (size_t)P_PATHS * IN_F * OUT_F;

    float* h       = ws + off_h;
    float* rsout   = ws + off_rsout;
    float* partial = ws + off_partial;
    float* beta    = ws + off_beta;
    int*   ibase   = (int*)(ws + off_i32);
    int*    bstart  = ibase + i_bstart;
    int*    bcursor = ibase + i_bcursor;
    uint_t* bcounts = (uint_t*)(ibase + i_bcounts);
    int*    rsn     = ibase + i_rsn;
    uint_t* dhist   = (uint_t*)(ibase + i_dhist);
    uint_t* ebuf    = (uint_t*)(ibase + i_ebuf);
    ushort_t* ubase = (ushort_t*)(ws + off_u16);
    ushort_t* xwb   = ubase + u_xwb;
    ushort_t* eidx2 = ubase + u_eidx2;
    ushort_t* Wt    = ubase + u_Wt;
    ushort_t* fcwb  = ubase + u_fcwb;

    // only bucket counters accumulate -> zero each call
    hipMemsetAsync(bcounts, 0, (size_t)P_PATHS * NBUCK * sizeof(uint_t), stream);

    prep_kernel<<<(P_PATHS * IN_F * OUT_F + 255) / 256, 256, 0, stream>>>(W, fc_w, Wt, fcwb);
    deghist_kernel<<<dim3(DSL, 2, P_PATHS), 256, 0, stream>>>(src, dhist);
    rsout_kernel<<<(P_PATHS * 2 * HALF_W + 255) / 256, 256, 0, stream>>>(dhist, rsout);
    bhist_kernel<<<dim3(NCHUNK, P_PATHS), 256, 0, stream>>>(dst, bcounts);
    bscan_kernel<<<1, 1024, 0, stream>>>(bcounts, bstart, bcursor);

    for (int p = 0; p < P_PATHS; ++p) {
        int sub = p * E_EDGES;
        gemm_xw_kernel<<<GBLK, 256, 0, stream>>>(
            x, Wt + ((size_t)p << 15), rsout + (size_t)p * N_NODES, xwb);
        bscatter_kernel<<<NCHUNK, 256, 0, stream>>>(
            src + (size_t)p * E_EDGES, dst + (size_t)p * E_EDGES,
            bcursor + (size_t)p * NBUCK, ebuf, sub);
        blocal_kernel<<<NBUCK, 256, 0, stream>>>(
            ebuf, bstart, eidx2, rsn, p * NBUCK, sub);
        gather_kernel<<<N_NODES / 4, 256, 0, stream>>>(
            xwb, eidx2, rsn, b_conv + p * OUT_F, h + (size_t)p * N_NODES * OUT_F);
        fc_mfma_kernel<<<GBLK, 256, 0, stream>>>(
            h + (size_t)p * N_NODES * OUT_F, fcwb, fc_b,
            partial + (size_t)p * GBLK * OUT_F);
    }
    beta_reduce_kernel<<<1, 512, 0, stream>>>(partial, att, beta);
    combine_kernel<<<(N_NODES * (OUT_F / 4) + 255) / 256, 256, 0, stream>>>(
        h, h_bias, beta, out);
}

// Round 6
// 361.731 us; speedup vs baseline: 9.0673x; 1.3080x over previous
//
#include <hip/hip_runtime.h>
#include <math.h>

#define N_NODES 50000
#define P_PATHS 4
#define E_EDGES 800000
#define IN_F 256
#define OUT_F 128
#define NPB 128                        // nodes per bucket
#define NBUCK 391                      // ceil(N/NPB)
#define NCHUNK 200                     // edge chunks per path
#define CHUNK_E (E_EDGES / NCHUNK)     // 4000
#define GBLK 391                       // row-blocks for gemm/fc (128 rows each)
#define DSL 20                         // edge slices for deg-out histogram
#define QTR 4                          // node quarters
#define Q_N 12500                      // nodes per quarter
#define Q_W 6250                       // packed u32 words per quarter (25KB LDS)
#define AP 264                         // LDS pitch (u16) for K=256 tiles
#define FP 136                         // LDS pitch (u16) for K=128 tiles

typedef unsigned short ushort_t;
typedef unsigned int uint_t;
typedef float f32x4 __attribute__((ext_vector_type(4)));
typedef short s16x8 __attribute__((ext_vector_type(8)));

__device__ __forceinline__ ushort_t f2bf(float f) {
    uint_t u = __float_as_uint(f);
    return (ushort_t)((u + 0x7FFFu + ((u >> 16) & 1u)) >> 16);   // RNE
}
__device__ __forceinline__ float bf2f(ushort_t h) {
    return __uint_as_float(((uint_t)h) << 16);
}

// ---------------- prep: W -> Wt bf16 (transposed [p][n][k]), fc_w -> bf16 ----------------
__global__ void prep_kernel(const float* __restrict__ W, const float* __restrict__ fcw,
                            ushort_t* __restrict__ Wt, ushort_t* __restrict__ fcwb)
{
    int idx = blockIdx.x * blockDim.x + threadIdx.x;
    if (idx < P_PATHS * IN_F * OUT_F) {          // 131072
        int p = idx >> 15;
        int r = idx & 32767;
        int k = r >> 7;
        int n = r & 127;
        Wt[((size_t)p << 15) + (size_t)n * IN_F + k] = f2bf(W[idx]);
    }
    if (idx < OUT_F * OUT_F) fcwb[idx] = f2bf(fcw[idx]);
}

// ---------------- deg_out: sliced quarter-range LDS histograms (packed 2×u16) ----------------
__global__ __launch_bounds__(256) void deghist_kernel(const int* __restrict__ src,
                                                      uint_t* __restrict__ dhist)
{
    __shared__ uint_t cnt[Q_W];   // 25 KB
    int sl = blockIdx.x, q = blockIdx.y, p = blockIdx.z;
    int t = threadIdx.x;
    int nbase = q * Q_N;
    for (int i = t; i < Q_W; i += 256) cnt[i] = 0;
    __syncthreads();
    const int4* s4 = (const int4*)(src + (size_t)p * E_EDGES + (size_t)sl * (E_EDGES / DSL));
    for (int i = t; i < E_EDGES / DSL / 4; i += 256) {
        int4 v = s4[i];
        uint_t r;
        r = (uint_t)(v.x - nbase); if (r < Q_N) atomicAdd(&cnt[r >> 1], 1u << ((r & 1) * 16));
        r = (uint_t)(v.y - nbase); if (r < Q_N) atomicAdd(&cnt[r >> 1], 1u << ((r & 1) * 16));
        r = (uint_t)(v.z - nbase); if (r < Q_N) atomicAdd(&cnt[r >> 1], 1u << ((r & 1) * 16));
        r = (uint_t)(v.w - nbase); if (r < Q_N) atomicAdd(&cnt[r >> 1], 1u << ((r & 1) * 16));
    }
    __syncthreads();
    uint_t* outp = dhist + (((size_t)p * QTR + q) * DSL + sl) * Q_W;
    for (int i = t; i < Q_W; i += 256) outp[i] = cnt[i];
}

// ---------------- merge slices -> rsout = rsqrt(max(deg_out,1)) ----------------
__global__ void rsout_kernel(const uint_t* __restrict__ dhist, float* __restrict__ rsout)
{
    int idx = blockIdx.x * 256 + threadIdx.x;      // over P*QTR*Q_W
    if (idx >= P_PATHS * QTR * Q_W) return;
    int ph = idx / Q_W;
    int w  = idx % Q_W;
    const uint_t* base = dhist + (size_t)ph * DSL * Q_W + w;
    uint_t s = 0;
#pragma unroll
    for (int sl = 0; sl < DSL; ++sl) s += base[(size_t)sl * Q_W];
    int p = ph >> 2, q = ph & 3;
    int node = q * Q_N + 2 * w;
    uint_t c0 = s & 0xFFFFu, c1 = s >> 16;
    rsout[(size_t)p * N_NODES + node]     = rsqrtf((float)(c0 ? c0 : 1u));
    rsout[(size_t)p * N_NODES + node + 1] = rsqrtf((float)(c1 ? c1 : 1u));
}

// ---------------- bucket histogram (by dst>>7), all paths ----------------
__global__ __launch_bounds__(256) void bhist_kernel(const int* __restrict__ dst,
                                                    uint_t* __restrict__ bcounts)
{
    __shared__ uint_t bh[NBUCK];
    int p = blockIdx.y;
    int t = threadIdx.x;
    for (int i = t; i < NBUCK; i += 256) bh[i] = 0;
    __syncthreads();
    const int4* d4 = (const int4*)(dst + (size_t)p * E_EDGES + (size_t)blockIdx.x * CHUNK_E);
    for (int i = t; i < CHUNK_E / 4; i += 256) {
        int4 v = d4[i];
        atomicAdd(&bh[v.x >> 7], 1u);
        atomicAdd(&bh[v.y >> 7], 1u);
        atomicAdd(&bh[v.z >> 7], 1u);
        atomicAdd(&bh[v.w >> 7], 1u);
    }
    __syncthreads();
    for (int i = t; i < NBUCK; i += 256)
        if (bh[i]) atomicAdd(&bcounts[p * NBUCK + i], bh[i]);
}

// ---------------- flat exclusive scan over P*NBUCK bucket counts ----------------
__global__ __launch_bounds__(1024) void bscan_kernel(const uint_t* __restrict__ bcounts,
                                                     int* __restrict__ bstart,
                                                     int* __restrict__ bcursor)
{
    __shared__ int a[2048], b[2048];
    int t = threadIdx.x;
    for (int i = t; i < 2048; i += 1024)
        a[i] = (i < P_PATHS * NBUCK) ? (int)bcounts[i] : 0;
    __syncthreads();
    int* pin = a; int* pout = b;
    for (int off = 1; off < 2048; off <<= 1) {
        for (int i = t; i < 2048; i += 1024)
            pout[i] = pin[i] + (i >= off ? pin[i - off] : 0);
        __syncthreads();
        int* tmp = pin; pin = pout; pout = tmp;
    }
    for (int i = t; i < P_PATHS * NBUCK; i += 1024) {
        int st = pin[i] - (int)bcounts[i];
        bstart[i] = st;
        bcursor[i] = st;
    }
    if (t == 0) bstart[P_PATHS * NBUCK] = pin[P_PATHS * NBUCK - 1];
}

// ---------------- scatter packed edges (src | dloc<<16) into bucket order, all paths ----------------
__global__ __launch_bounds__(256) void bscatter_kernel(const int* __restrict__ src,
                                                       const int* __restrict__ dst,
                                                       int* __restrict__ bcursor,
                                                       uint_t* __restrict__ ebuf)
{
    __shared__ uint_t bh[NBUCK];
    __shared__ uint_t lbase[NBUCK];
    int p = blockIdx.y;
    int t = threadIdx.x;
    int sub = p * E_EDGES;
    int* bcursor_p = bcursor + p * NBUCK;
    uint_t* ebuf_p = ebuf + (size_t)p * E_EDGES;
    for (int i = t; i < NBUCK; i += 256) bh[i] = 0;
    __syncthreads();
    size_t ebase = (size_t)p * E_EDGES + (size_t)blockIdx.x * CHUNK_E;
    const int4* d4 = (const int4*)(dst + ebase);
    const int4* s4 = (const int4*)(src + ebase);
    for (int i = t; i < CHUNK_E / 4; i += 256) {
        int4 v = d4[i];
        atomicAdd(&bh[v.x >> 7], 1u);
        atomicAdd(&bh[v.y >> 7], 1u);
        atomicAdd(&bh[v.z >> 7], 1u);
        atomicAdd(&bh[v.w >> 7], 1u);
    }
    __syncthreads();
    for (int i = t; i < NBUCK; i += 256) {
        uint_t c = bh[i];
        lbase[i] = c ? (uint_t)(atomicAdd(&bcursor_p[i], (int)c) - sub) : 0u;
        bh[i] = 0;     // reuse as local cursor
    }
    __syncthreads();
    for (int i = t; i < CHUNK_E / 4; i += 256) {
        int4 d = d4[i];
        int4 s = s4[i];
        { int bk = d.x >> 7; uint_t pos = lbase[bk] + atomicAdd(&bh[bk], 1u); ebuf_p[pos] = (uint_t)s.x | ((uint_t)(d.x & 127) << 16); }
        { int bk = d.y >> 7; uint_t pos = lbase[bk] + atomicAdd(&bh[bk], 1u); ebuf_p[pos] = (uint_t)s.y | ((uint_t)(d.y & 127) << 16); }
        { int bk = d.z >> 7; uint_t pos = lbase[bk] + atomicAdd(&bh[bk], 1u); ebuf_p[pos] = (uint_t)s.z | ((uint_t)(d.z & 127) << 16); }
        { int bk = d.w >> 7; uint_t pos = lbase[bk] + atomicAdd(&bh[bk], 1u); ebuf_p[pos] = (uint_t)s.w | ((uint_t)(d.w & 127) << 16); }
    }
}

// ---------------- per-bucket local CSR build, all paths ----------------
__global__ __launch_bounds__(256) void blocal_kernel(const uint_t* __restrict__ ebuf,
                                                     const int* __restrict__ bstart,
                                                     ushort_t* __restrict__ eidx2,
                                                     int* __restrict__ rsn)
{
    __shared__ uint_t hist[NPB];
    __shared__ uint_t cur[NPB];
    __shared__ uint_t sa[NPB], sb[NPB];
    int bkt = blockIdx.x;
    int p = blockIdx.y;
    int t = threadIdx.x;
    int sub = p * E_EDGES;
    const uint_t* ebuf_p = ebuf + (size_t)p * E_EDGES;
    ushort_t* eidx2_p = eidx2 + (size_t)p * E_EDGES;
    int* rsn_p = rsn + (size_t)p * (N_NODES + 1);
    if (t < NPB) hist[t] = 0;
    __syncthreads();
    int r0 = bstart[p * NBUCK + bkt] - sub;
    int r1 = bstart[p * NBUCK + bkt + 1] - sub;
    for (int e = r0 + t; e < r1; e += 256)
        atomicAdd(&hist[ebuf_p[e] >> 16], 1u);
    __syncthreads();
    if (t < NPB) sa[t] = hist[t];
    __syncthreads();
    uint_t* pin = sa; uint_t* pout = sb;
    for (int off = 1; off < NPB; off <<= 1) {
        if (t < NPB) pout[t] = pin[t] + (t >= off ? pin[t - off] : 0u);
        __syncthreads();
        uint_t* tmp = pin; pin = pout; pout = tmp;
    }
    if (t < NPB) {
        uint_t ex = pin[t] - hist[t];
        int node = bkt * NPB + t;
        if (node < N_NODES) rsn_p[node] = r0 + (int)ex;
        cur[t] = ex;
    }
    if (bkt == NBUCK - 1 && t == 0) rsn_p[N_NODES] = r1;   // == E_EDGES
    __syncthreads();
    for (int e = r0 + t; e < r1; e += 256) {
        uint_t pk = ebuf_p[e];
        int dl = (int)(pk >> 16);
        uint_t pos = atomicAdd(&cur[dl], 1u);
        eidx2_p[r0 + pos] = (ushort_t)(pk & 0xFFFFu);
    }
}

// ---------------- MFMA GEMM all paths: xwb[p] = bf16( (x @ Wt[p]^T) * rsout[p] ) ----------------
// A (x rows, bf16) staged ONCE full-K; loop p: stage B, 512 MFMA, store.
__global__ __launch_bounds__(256) void gemm_xall_kernel(const float* __restrict__ x,
                                                        const ushort_t* __restrict__ Wt,
                                                        const float* __restrict__ rsout,
                                                        ushort_t* __restrict__ xwb)
{
    __shared__ ushort_t As[128 * AP];   // 66 KB
    __shared__ ushort_t Bs[128 * AP];   // 66 KB
    int m0 = blockIdx.x * 128;
    int t = threadIdx.x;
    int wid = t >> 6, lane = t & 63;
    int wr = wid >> 1, wc = wid & 1;
    int srow = t >> 1, half = (t & 1) * 16;
    int gr = m0 + srow;
    // stage A full-K (fp32 -> bf16)
#pragma unroll
    for (int c = 0; c < 8; ++c) {
        int kb = c * 32 + half;
        uint4 w0 = make_uint4(0, 0, 0, 0), w1 = make_uint4(0, 0, 0, 0);
        if (gr < N_NODES) {
            const float* ap = x + (size_t)gr * IN_F + kb;
            float4 f0 = *(const float4*)(ap + 0);
            float4 f1 = *(const float4*)(ap + 4);
            float4 f2 = *(const float4*)(ap + 8);
            float4 f3 = *(const float4*)(ap + 12);
            w0.x = (uint_t)f2bf(f0.x) | ((uint_t)f2bf(f0.y) << 16);
            w0.y = (uint_t)f2bf(f0.z) | ((uint_t)f2bf(f0.w) << 16);
            w0.z = (uint_t)f2bf(f1.x) | ((uint_t)f2bf(f1.y) << 16);
            w0.w = (uint_t)f2bf(f1.z) | ((uint_t)f2bf(f1.w) << 16);
            w1.x = (uint_t)f2bf(f2.x) | ((uint_t)f2bf(f2.y) << 16);
            w1.y = (uint_t)f2bf(f2.z) | ((uint_t)f2bf(f2.w) << 16);
            w1.z = (uint_t)f2bf(f3.x) | ((uint_t)f2bf(f3.y) << 16);
            w1.w = (uint_t)f2bf(f3.z) | ((uint_t)f2bf(f3.w) << 16);
        }
        *(uint4*)&As[srow * AP + kb]     = w0;
        *(uint4*)&As[srow * AP + kb + 8] = w1;
    }
    for (int p = 0; p < P_PATHS; ++p) {
        __syncthreads();   // As ready / prev path's MFMA reads done
        const ushort_t* Wp = Wt + ((size_t)p << 15);
#pragma unroll
        for (int c = 0; c < 8; ++c) {
            int kb = c * 32 + half;
            const ushort_t* bp = Wp + (size_t)srow * IN_F + kb;
            *(uint4*)&Bs[srow * AP + kb]     = *(const uint4*)(bp);
            *(uint4*)&Bs[srow * AP + kb + 8] = *(const uint4*)(bp + 8);
        }
        __syncthreads();
        f32x4 acc[4][4] = {};
#pragma unroll
        for (int k0 = 0; k0 < IN_F; k0 += 32) {
            s16x8 aF[4], bF[4];
            int kk = k0 + (lane >> 4) * 8;
#pragma unroll
            for (int m = 0; m < 4; ++m)
                aF[m] = *(const s16x8*)&As[(wr * 64 + m * 16 + (lane & 15)) * AP + kk];
#pragma unroll
            for (int n = 0; n < 4; ++n)
                bF[n] = *(const s16x8*)&Bs[(wc * 64 + n * 16 + (lane & 15)) * AP + kk];
#pragma unroll
            for (int m = 0; m < 4; ++m)
#pragma unroll
                for (int n = 0; n < 4; ++n)
                    acc[m][n] = __builtin_amdgcn_mfma_f32_16x16x32_bf16(aF[m], bF[n], acc[m][n], 0, 0, 0);
        }
        ushort_t* xp = xwb + (size_t)p * N_NODES * OUT_F;
        const float* rp = rsout + (size_t)p * N_NODES;
#pragma unroll
        for (int m = 0; m < 4; ++m) {
#pragma unroll
            for (int i = 0; i < 4; ++i) {
                int row = m0 + wr * 64 + m * 16 + (lane >> 4) * 4 + i;
                if (row < N_NODES) {
                    float rs = rp[row];
#pragma unroll
                    for (int n = 0; n < 4; ++n) {
                        int col = wc * 64 + n * 16 + (lane & 15);
                        xp[(size_t)row * OUT_F + col] = f2bf(acc[m][n][i] * rs);
                    }
                }
            }
        }
    }
}

// ---------------- gather all paths: one wave per node; h(bf16) = agg*rsqrt(deg)+b_conv ----------------
__global__ __launch_bounds__(256) void gather_kernel(const ushort_t* __restrict__ xwb,
                                                     const ushort_t* __restrict__ eidx2,
                                                     const int* __restrict__ rsn,
                                                     const float* __restrict__ bconv,
                                                     uint_t* __restrict__ hb)   // u32 view (2×bf16)
{
    int wid = threadIdx.x >> 6, lane = threadIdx.x & 63;
    int p = blockIdx.y;
    int n = blockIdx.x * 4 + wid;
    const int* rsn_p = rsn + (size_t)p * (N_NODES + 1);
    const ushort_t* eidx2_p = eidx2 + (size_t)p * E_EDGES;
    int b = rsn_p[n], e = rsn_p[n + 1];
    const uint_t* base = (const uint_t*)xwb + (size_t)p * N_NODES * 64 + lane;
    float a0 = 0.f, a1 = 0.f;
    int i = b;
    for (; i + 3 < e; i += 4) {
        int s0 = eidx2_p[i], s1 = eidx2_p[i + 1], s2 = eidx2_p[i + 2], s3 = eidx2_p[i + 3];
        uint_t w0 = base[(size_t)s0 * 64];
        uint_t w1 = base[(size_t)s1 * 64];
        uint_t w2 = base[(size_t)s2 * 64];
        uint_t w3 = base[(size_t)s3 * 64];
        a0 += (bf2f((ushort_t)w0) + bf2f((ushort_t)w1)) + (bf2f((ushort_t)w2) + bf2f((ushort_t)w3));
        a1 += (bf2f((ushort_t)(w0 >> 16)) + bf2f((ushort_t)(w1 >> 16))) +
              (bf2f((ushort_t)(w2 >> 16)) + bf2f((ushort_t)(w3 >> 16)));
    }
    for (; i < e; ++i) {
        int s = eidx2_p[i];
        uint_t w = base[(size_t)s * 64];
        a0 += bf2f((ushort_t)w);
        a1 += bf2f((ushort_t)(w >> 16));
    }
    int d = e - b;
    float sc = rsqrtf((float)(d > 0 ? d : 1));
    float2 bc = *(const float2*)(bconv + (size_t)p * OUT_F + 2 * lane);
    float r0 = fmaf(a0, sc, bc.x);
    float r1 = fmaf(a1, sc, bc.y);
    hb[((size_t)p * N_NODES + n) * 64 + lane] = (uint_t)f2bf(r0) | ((uint_t)f2bf(r1) << 16);
}

// ---------------- MFMA fc (bf16 h in) + tanh + per-block column sums, all paths ----------------
__global__ __launch_bounds__(256) void fc_mfma_kernel(const ushort_t* __restrict__ hb,
                                                      const ushort_t* __restrict__ fcwb,
                                                      const float* __restrict__ fcb,
                                                      float* __restrict__ partial)
{
    __shared__ ushort_t As[128 * FP];   // 34 KB
    __shared__ ushort_t Bs[128 * FP];
    __shared__ float red[2][128];
    int m0 = blockIdx.x * 128;
    int p = blockIdx.y;
    int t = threadIdx.x;
    int wid = t >> 6, lane = t & 63;
    int wr = wid >> 1, wc = wid & 1;
    int srow = t >> 1, half = (t & 1) * 16;
    int gr = m0 + srow;
    const ushort_t* hp = hb + (size_t)p * N_NODES * OUT_F;
#pragma unroll
    for (int c = 0; c < 4; ++c) {
        int kb = c * 32 + half;
        uint4 w0 = make_uint4(0, 0, 0, 0), w1 = make_uint4(0, 0, 0, 0);
        if (gr < N_NODES) {
            const ushort_t* ap = hp + (size_t)gr * OUT_F + kb;
            w0 = *(const uint4*)(ap);
            w1 = *(const uint4*)(ap + 8);
        }
        *(uint4*)&As[srow * FP + kb]     = w0;
        *(uint4*)&As[srow * FP + kb + 8] = w1;
        const ushort_t* bp = fcwb + (size_t)srow * OUT_F + kb;
        *(uint4*)&Bs[srow * FP + kb]     = *(const uint4*)(bp);
        *(uint4*)&Bs[srow * FP + kb + 8] = *(const uint4*)(bp + 8);
    }
    __syncthreads();
    f32x4 acc[4][4] = {};
#pragma unroll
    for (int k0 = 0; k0 < OUT_F; k0 += 32) {
        s16x8 aF[4], bF[4];
        int kk = k0 + (lane >> 4) * 8;
#pragma unroll
        for (int m = 0; m < 4; ++m)
            aF[m] = *(const s16x8*)&As[(wr * 64 + m * 16 + (lane & 15)) * FP + kk];
#pragma unroll
        for (int n = 0; n < 4; ++n)
            bF[n] = *(const s16x8*)&Bs[(wc * 64 + n * 16 + (lane & 15)) * FP + kk];
#pragma unroll
        for (int m = 0; m < 4; ++m)
#pragma unroll
            for (int n = 0; n < 4; ++n)
                acc[m][n] = __builtin_amdgcn_mfma_f32_16x16x32_bf16(aF[m], bF[n], acc[m][n], 0, 0, 0);
    }
#pragma unroll
    for (int n = 0; n < 4; ++n) {
        int col = wc * 64 + n * 16 + (lane & 15);
        float fb = fcb[col];
        float s = 0.f;
#pragma unroll
        for (int m = 0; m < 4; ++m)
#pragma unroll
            for (int i = 0; i < 4; ++i) {
                int row = m0 + wr * 64 + m * 16 + (lane >> 4) * 4 + i;
                if (row < N_NODES) s += tanhf(acc[m][n][i] + fb);
            }
        s += __shfl_xor(s, 16);
        s += __shfl_xor(s, 32);
        if (lane < 16) red[wr][col] = s;
    }
    __syncthreads();
    if (t < 128)
        partial[((size_t)p * GBLK + blockIdx.x) * OUT_F + t] = red[0][t] + red[1][t];
}

// ---------------- reduce partials -> sp -> beta softmax ----------------
__global__ __launch_bounds__(512) void beta_reduce_kernel(const float* __restrict__ partial,
                                                          const float* __restrict__ att,
                                                          float* __restrict__ beta)
{
    int t = threadIdx.x;          // 512 = P*128
    int p = t >> 7, c = t & 127;
    float s = 0.f;
    for (int i = 0; i < GBLK; ++i)
        s += partial[((size_t)p * GBLK + i) * OUT_F + c];
    float v = att[p * OUT_F + c] * (s * (1.0f / N_NODES));
    __shared__ float red[512];
    red[t] = v;
    __syncthreads();
    for (int off = 64; off >= 1; off >>= 1) {
        if (c < off) red[t] += red[t + off];
        __syncthreads();
    }
    if (t == 0) {
        float w[P_PATHS], mx = -1e30f;
        for (int q = 0; q < P_PATHS; ++q) { w[q] = red[q * 128]; mx = fmaxf(mx, w[q]); }
        float sum = 0.f;
        for (int q = 0; q < P_PATHS; ++q) { w[q] = expf(w[q] - mx); sum += w[q]; }
        for (int q = 0; q < P_PATHS; ++q) beta[q] = w[q] / sum;
    }
}

// ---------------- out = sum_p beta[p]*h[p] + h_bias ----------------
__global__ void combine_kernel(const uint_t* __restrict__ hb, const float* __restrict__ hbias,
                               const float* __restrict__ beta, float* __restrict__ out)
{
    int idx = blockIdx.x * blockDim.x + threadIdx.x;   // over N*64
    if (idx >= N_NODES * 64) return;
    int n = idx >> 6;
    int w = idx & 63;
    float2 hbv = *(const float2*)(hbias + 2 * w);
    float r0 = hbv.x, r1 = hbv.y;
#pragma unroll
    for (int p = 0; p < P_PATHS; ++p) {
        float bp = beta[p];
        uint_t v = hb[((size_t)p * N_NODES + n) * 64 + w];
        r0 = fmaf(bp, bf2f((ushort_t)v), r0);
        r1 = fmaf(bp, bf2f((ushort_t)(v >> 16)), r1);
    }
    *(float2*)(out + (size_t)n * OUT_F + 2 * w) = make_float2(r0, r1);
}

extern "C" void kernel_launch(void* const* d_in, const int* in_sizes, int n_in,
                              void* d_out, int out_size, void* d_ws, size_t ws_size,
                              hipStream_t stream)
{
    const float* x      = (const float*)d_in[0];
    const float* W      = (const float*)d_in[1];
    const float* b_conv = (const float*)d_in[2];
    const float* att    = (const float*)d_in[3];
    const float* fc_w   = (const float*)d_in[4];
    const float* fc_b   = (const float*)d_in[5];
    const float* h_bias = (const float*)d_in[6];
    const int*   src    = (const int*)d_in[7];
    const int*   dst    = (const int*)d_in[8];
    float* out = (float*)d_out;
    float* ws  = (float*)d_ws;

    // ---- ws layout, total ~132.3 MB ----
    size_t off_rsout   = 0;                                            // P*N f32
    size_t off_partial = off_rsout + (size_t)P_PATHS * N_NODES;        // P*GBLK*128 f32
    size_t off_beta    = off_partial + (size_t)P_PATHS * GBLK * OUT_F;
    size_t off_i32     = (off_beta + 4 + 63) & ~(size_t)63;
    // int region (units of int)
    size_t i_bstart  = 0;                                  // P*NBUCK+1 -> pad 1600
    size_t i_bcursor = 1600;                               // P*NBUCK   -> pad 1600
    size_t i_bcounts = 3200;                               // P*NBUCK   -> pad 1600
    size_t i_rsn     = 4800;                               // P*(N+1) = 200004 -> pad 200064
    size_t i_dhist   = 204864;                             // P*QTR*DSL*Q_W = 2,000,000
    size_t i_ebuf    = i_dhist + (size_t)P_PATHS * QTR * DSL * Q_W;   // P*E
    size_t n_ints    = i_ebuf + (size_t)P_PATHS * E_EDGES;
    size_t off_u16   = off_i32 + ((n_ints + 63) & ~(size_t)63);
    // ushort region (units of ushort)
    size_t u_hb    = 0;                                    // P*N*128
    size_t u_xwb   = u_hb + (size_t)P_PATHS * N_NODES * OUT_F;   // P*N*128
    size_t u_eidx2 = u_xwb + (size_t)P_PATHS * N_NODES * OUT_F;  // P*E
    size_t u_Wt    = u_eidx2 + (size_t)P_PATHS * E_EDGES;        // P*IN*OUT
    size_t u_fcwb  = u_Wt + (size_t)P_PATHS * IN_F * OUT_F;      // OUT*OUT

    float* rsout   = ws + off_rsout;
    float* partial = ws + off_partial;
    float* beta    = ws + off_beta;
    int*   ibase   = (int*)(ws + off_i32);
    int*    bstart  = ibase + i_bstart;
    int*    bcursor = ibase + i_bcursor;
    uint_t* bcounts = (uint_t*)(ibase + i_bcounts);
    int*    rsn     = ibase + i_rsn;
    uint_t* dhist   = (uint_t*)(ibase + i_dhist);
    uint_t* ebuf    = (uint_t*)(ibase + i_ebuf);
    ushort_t* ubase = (ushort_t*)(ws + off_u16);
    ushort_t* hb    = ubase + u_hb;
    ushort_t* xwb   = ubase + u_xwb;
    ushort_t* eidx2 = ubase + u_eidx2;
    ushort_t* Wt    = ubase + u_Wt;
    ushort_t* fcwb  = ubase + u_fcwb;

    // only bucket counters accumulate -> zero each call
    hipMemsetAsync(bcounts, 0, (size_t)P_PATHS * NBUCK * sizeof(uint_t), stream);

    prep_kernel<<<(P_PATHS * IN_F * OUT_F + 255) / 256, 256, 0, stream>>>(W, fc_w, Wt, fcwb);
    deghist_kernel<<<dim3(DSL, QTR, P_PATHS), 256, 0, stream>>>(src, dhist);
    rsout_kernel<<<(P_PATHS * QTR * Q_W + 255) / 256, 256, 0, stream>>>(dhist, rsout);
    bhist_kernel<<<dim3(NCHUNK, P_PATHS), 256, 0, stream>>>(dst, bcounts);
    bscan_kernel<<<1, 1024, 0, stream>>>(bcounts, bstart, bcursor);

    gemm_xall_kernel<<<GBLK, 256, 0, stream>>>(x, Wt, rsout, xwb);
    bscatter_kernel<<<dim3(NCHUNK, P_PATHS), 256, 0, stream>>>(src, dst, bcursor, ebuf);
    blocal_kernel<<<dim3(NBUCK, P_PATHS), 256, 0, stream>>>(ebuf, bstart, eidx2, rsn);
    gather_kernel<<<dim3(N_NODES / 4, P_PATHS), 256, 0, stream>>>(
        xwb, eidx2, rsn, b_conv, (uint_t*)hb);
    fc_mfma_kernel<<<dim3(GBLK, P_PATHS), 256, 0, stream>>>(hb, fcwb, fc_b, partial);

    beta_reduce_kernel<<<1, 512, 0, stream>>>(partial, att, beta);
    combine_kernel<<<(N_NODES * 64 + 255) / 256, 256, 0, stream>>>(
        (const uint_t*)hb, h_bias, beta, out);
}

// Round 7
// 331.226 us; speedup vs baseline: 9.9024x; 1.0921x over previous
//
#include <hip/hip_runtime.h>
#include <math.h>

#define N_NODES 50000
#define P_PATHS 4
#define E_EDGES 800000
#define IN_F 256
#define OUT_F 128
#define NPB 128                        // nodes per bucket
#define NBUCK 391                      // ceil(N/NPB)
#define NCHUNK 200                     // edge chunks per path
#define CHUNK_E (E_EDGES / NCHUNK)     // 4000
#define GBLK 391                       // row-blocks for gemm/fc (128 rows each)
#define DSL 20                         // edge slices for deg-out histogram
#define QTR 4                          // node quarters
#define Q_N 12500                      // nodes per quarter
#define Q_W 6250                       // packed u32 words per quarter (25KB LDS)
#define AP 264                         // LDS pitch (u16) for K=256 tiles
#define FP 136                         // LDS pitch (u16) for K=128 tiles
#define RSB 196                        // rsout blocks in merged rsout+bscan

typedef unsigned short ushort_t;
typedef unsigned int uint_t;
typedef float f32x4 __attribute__((ext_vector_type(4)));
typedef short s16x8 __attribute__((ext_vector_type(8)));

__device__ __forceinline__ ushort_t f2bf(float f) {
    uint_t u = __float_as_uint(f);
    return (ushort_t)((u + 0x7FFFu + ((u >> 16) & 1u)) >> 16);   // RNE
}
__device__ __forceinline__ float bf2f(ushort_t h) {
    return __uint_as_float(((uint_t)h) << 16);
}

// ---------------- prep: W -> Wt bf16 (transposed [p][n][k]), fc_w -> bf16 ----------------
__global__ void prep_kernel(const float* __restrict__ W, const float* __restrict__ fcw,
                            ushort_t* __restrict__ Wt, ushort_t* __restrict__ fcwb)
{
    int idx = blockIdx.x * blockDim.x + threadIdx.x;
    if (idx < P_PATHS * IN_F * OUT_F) {          // 131072
        int p = idx >> 15;
        int r = idx & 32767;
        int k = r >> 7;
        int n = r & 127;
        Wt[((size_t)p << 15) + (size_t)n * IN_F + k] = f2bf(W[idx]);
    }
    if (idx < OUT_F * OUT_F) fcwb[idx] = f2bf(fcw[idx]);
}

// ---------------- deg_out hist (q<QTR) + dst bucket hist (q==QTR), per edge slice ----------------
__global__ __launch_bounds__(256) void deghist_kernel(const int* __restrict__ src,
                                                      const int* __restrict__ dst,
                                                      uint_t* __restrict__ dhist,
                                                      uint_t* __restrict__ bcounts)
{
    __shared__ uint_t cnt[Q_W];   // 25 KB (dst-hist blocks use first NBUCK words)
    int sl = blockIdx.x, q = blockIdx.y, p = blockIdx.z;
    int t = threadIdx.x;
    if (q == QTR) {
        // bucket histogram (by dst>>7) for this slice
        for (int i = t; i < NBUCK; i += 256) cnt[i] = 0;
        __syncthreads();
        const int4* d4 = (const int4*)(dst + (size_t)p * E_EDGES + (size_t)sl * (E_EDGES / DSL));
        for (int i = t; i < E_EDGES / DSL / 4; i += 256) {
            int4 v = d4[i];
            atomicAdd(&cnt[v.x >> 7], 1u);
            atomicAdd(&cnt[v.y >> 7], 1u);
            atomicAdd(&cnt[v.z >> 7], 1u);
            atomicAdd(&cnt[v.w >> 7], 1u);
        }
        __syncthreads();
        for (int i = t; i < NBUCK; i += 256)
            if (cnt[i]) atomicAdd(&bcounts[p * NBUCK + i], cnt[i]);
        return;
    }
    int nbase = q * Q_N;
    for (int i = t; i < Q_W; i += 256) cnt[i] = 0;
    __syncthreads();
    const int4* s4 = (const int4*)(src + (size_t)p * E_EDGES + (size_t)sl * (E_EDGES / DSL));
    for (int i = t; i < E_EDGES / DSL / 4; i += 256) {
        int4 v = s4[i];
        uint_t r;
        r = (uint_t)(v.x - nbase); if (r < Q_N) atomicAdd(&cnt[r >> 1], 1u << ((r & 1) * 16));
        r = (uint_t)(v.y - nbase); if (r < Q_N) atomicAdd(&cnt[r >> 1], 1u << ((r & 1) * 16));
        r = (uint_t)(v.z - nbase); if (r < Q_N) atomicAdd(&cnt[r >> 1], 1u << ((r & 1) * 16));
        r = (uint_t)(v.w - nbase); if (r < Q_N) atomicAdd(&cnt[r >> 1], 1u << ((r & 1) * 16));
    }
    __syncthreads();
    uint_t* outp = dhist + (((size_t)p * QTR + q) * DSL + sl) * Q_W;
    for (int i = t; i < Q_W; i += 256) outp[i] = cnt[i];
}

// ---------------- merged: blocks 0..RSB-1 -> rsout; block RSB -> bucket scan ----------------
__global__ __launch_bounds__(1024) void rsout_bscan_kernel(const uint_t* __restrict__ dhist,
                                                           float* __restrict__ rsout,
                                                           const uint_t* __restrict__ bcounts,
                                                           int* __restrict__ bstart,
                                                           int* __restrict__ bcursor)
{
    int t = threadIdx.x;
    if (blockIdx.x == RSB) {
        __shared__ int a[2048], b[2048];
        for (int i = t; i < 2048; i += 1024)
            a[i] = (i < P_PATHS * NBUCK) ? (int)bcounts[i] : 0;
        __syncthreads();
        int* pin = a; int* pout = b;
        for (int off = 1; off < 2048; off <<= 1) {
            for (int i = t; i < 2048; i += 1024)
                pout[i] = pin[i] + (i >= off ? pin[i - off] : 0);
            __syncthreads();
            int* tmp = pin; pin = pout; pout = tmp;
        }
        for (int i = t; i < P_PATHS * NBUCK; i += 1024) {
            int st = pin[i] - (int)bcounts[i];
            bstart[i] = st;
            bcursor[i] = st;
        }
        if (t == 0) bstart[P_PATHS * NBUCK] = pin[P_PATHS * NBUCK - 1];
        return;
    }
    int idx = blockIdx.x * 1024 + t;      // over P*QTR*Q_W
    if (idx >= P_PATHS * QTR * Q_W) return;
    int ph = idx / Q_W;
    int w  = idx % Q_W;
    const uint_t* base = dhist + (size_t)ph * DSL * Q_W + w;
    uint_t s = 0;
#pragma unroll
    for (int sl = 0; sl < DSL; ++sl) s += base[(size_t)sl * Q_W];
    int p = ph >> 2, q = ph & 3;
    int node = q * Q_N + 2 * w;
    uint_t c0 = s & 0xFFFFu, c1 = s >> 16;
    rsout[(size_t)p * N_NODES + node]     = rsqrtf((float)(c0 ? c0 : 1u));
    rsout[(size_t)p * N_NODES + node + 1] = rsqrtf((float)(c1 ? c1 : 1u));
}

// ---------------- scatter packed edges (src | dloc<<16) into bucket order, all paths ----------------
__global__ __launch_bounds__(256) void bscatter_kernel(const int* __restrict__ src,
                                                       const int* __restrict__ dst,
                                                       int* __restrict__ bcursor,
                                                       uint_t* __restrict__ ebuf)
{
    __shared__ uint_t bh[NBUCK];
    __shared__ uint_t lbase[NBUCK];
    int p = blockIdx.y;
    int t = threadIdx.x;
    int sub = p * E_EDGES;
    int* bcursor_p = bcursor + p * NBUCK;
    uint_t* ebuf_p = ebuf + (size_t)p * E_EDGES;
    for (int i = t; i < NBUCK; i += 256) bh[i] = 0;
    __syncthreads();
    size_t ebase = (size_t)p * E_EDGES + (size_t)blockIdx.x * CHUNK_E;
    const int4* d4 = (const int4*)(dst + ebase);
    const int4* s4 = (const int4*)(src + ebase);
    for (int i = t; i < CHUNK_E / 4; i += 256) {
        int4 v = d4[i];
        atomicAdd(&bh[v.x >> 7], 1u);
        atomicAdd(&bh[v.y >> 7], 1u);
        atomicAdd(&bh[v.z >> 7], 1u);
        atomicAdd(&bh[v.w >> 7], 1u);
    }
    __syncthreads();
    for (int i = t; i < NBUCK; i += 256) {
        uint_t c = bh[i];
        lbase[i] = c ? (uint_t)(atomicAdd(&bcursor_p[i], (int)c) - sub) : 0u;
        bh[i] = 0;     // reuse as local cursor
    }
    __syncthreads();
    for (int i = t; i < CHUNK_E / 4; i += 256) {
        int4 d = d4[i];
        int4 s = s4[i];
        { int bk = d.x >> 7; uint_t pos = lbase[bk] + atomicAdd(&bh[bk], 1u); ebuf_p[pos] = (uint_t)s.x | ((uint_t)(d.x & 127) << 16); }
        { int bk = d.y >> 7; uint_t pos = lbase[bk] + atomicAdd(&bh[bk], 1u); ebuf_p[pos] = (uint_t)s.y | ((uint_t)(d.y & 127) << 16); }
        { int bk = d.z >> 7; uint_t pos = lbase[bk] + atomicAdd(&bh[bk], 1u); ebuf_p[pos] = (uint_t)s.z | ((uint_t)(d.z & 127) << 16); }
        { int bk = d.w >> 7; uint_t pos = lbase[bk] + atomicAdd(&bh[bk], 1u); ebuf_p[pos] = (uint_t)s.w | ((uint_t)(d.w & 127) << 16); }
    }
}

// ---------------- per-bucket local CSR build, all paths ----------------
__global__ __launch_bounds__(256) void blocal_kernel(const uint_t* __restrict__ ebuf,
                                                     const int* __restrict__ bstart,
                                                     ushort_t* __restrict__ eidx2,
                                                     int* __restrict__ rsn)
{
    __shared__ uint_t hist[NPB];
    __shared__ uint_t cur[NPB];
    __shared__ uint_t sa[NPB], sb[NPB];
    int bkt = blockIdx.x;
    int p = blockIdx.y;
    int t = threadIdx.x;
    int sub = p * E_EDGES;
    const uint_t* ebuf_p = ebuf + (size_t)p * E_EDGES;
    ushort_t* eidx2_p = eidx2 + (size_t)p * E_EDGES;
    int* rsn_p = rsn + (size_t)p * (N_NODES + 1);
    if (t < NPB) hist[t] = 0;
    __syncthreads();
    int r0 = bstart[p * NBUCK + bkt] - sub;
    int r1 = bstart[p * NBUCK + bkt + 1] - sub;
    for (int e = r0 + t; e < r1; e += 256)
        atomicAdd(&hist[ebuf_p[e] >> 16], 1u);
    __syncthreads();
    if (t < NPB) sa[t] = hist[t];
    __syncthreads();
    uint_t* pin = sa; uint_t* pout = sb;
    for (int off = 1; off < NPB; off <<= 1) {
        if (t < NPB) pout[t] = pin[t] + (t >= off ? pin[t - off] : 0u);
        __syncthreads();
        uint_t* tmp = pin; pin = pout; pout = tmp;
    }
    if (t < NPB) {
        uint_t ex = pin[t] - hist[t];
        int node = bkt * NPB + t;
        if (node < N_NODES) rsn_p[node] = r0 + (int)ex;
        cur[t] = ex;
    }
    if (bkt == NBUCK - 1 && t == 0) rsn_p[N_NODES] = r1;   // == E_EDGES
    __syncthreads();
    for (int e = r0 + t; e < r1; e += 256) {
        uint_t pk = ebuf_p[e];
        int dl = (int)(pk >> 16);
        uint_t pos = atomicAdd(&cur[dl], 1u);
        eidx2_p[r0 + pos] = (ushort_t)(pk & 0xFFFFu);
    }
}

// ---------------- MFMA GEMM, path-pair per block: xwb[p] = bf16( (x @ Wt[p]^T) * rsout[p] ) ----------------
__global__ __launch_bounds__(256) void gemm_xall_kernel(const float* __restrict__ x,
                                                        const ushort_t* __restrict__ Wt,
                                                        const float* __restrict__ rsout,
                                                        ushort_t* __restrict__ xwb)
{
    __shared__ ushort_t As[128 * AP];   // 66 KB
    __shared__ ushort_t Bs[128 * AP];   // 66 KB
    int m0 = blockIdx.x * 128;
    int t = threadIdx.x;
    int wid = t >> 6, lane = t & 63;
    int wr = wid >> 1, wc = wid & 1;
    int srow = t >> 1, half = (t & 1) * 16;
    int gr = m0 + srow;
    // stage A full-K (fp32 -> bf16)
#pragma unroll
    for (int c = 0; c < 8; ++c) {
        int kb = c * 32 + half;
        uint4 w0 = make_uint4(0, 0, 0, 0), w1 = make_uint4(0, 0, 0, 0);
        if (gr < N_NODES) {
            const float* ap = x + (size_t)gr * IN_F + kb;
            float4 f0 = *(const float4*)(ap + 0);
            float4 f1 = *(const float4*)(ap + 4);
            float4 f2 = *(const float4*)(ap + 8);
            float4 f3 = *(const float4*)(ap + 12);
            w0.x = (uint_t)f2bf(f0.x) | ((uint_t)f2bf(f0.y) << 16);
            w0.y = (uint_t)f2bf(f0.z) | ((uint_t)f2bf(f0.w) << 16);
            w0.z = (uint_t)f2bf(f1.x) | ((uint_t)f2bf(f1.y) << 16);
            w0.w = (uint_t)f2bf(f1.z) | ((uint_t)f2bf(f1.w) << 16);
            w1.x = (uint_t)f2bf(f2.x) | ((uint_t)f2bf(f2.y) << 16);
            w1.y = (uint_t)f2bf(f2.z) | ((uint_t)f2bf(f2.w) << 16);
            w1.z = (uint_t)f2bf(f3.x) | ((uint_t)f2bf(f3.y) << 16);
            w1.w = (uint_t)f2bf(f3.z) | ((uint_t)f2bf(f3.w) << 16);
        }
        *(uint4*)&As[srow * AP + kb]     = w0;
        *(uint4*)&As[srow * AP + kb + 8] = w1;
    }
    for (int pp = 0; pp < 2; ++pp) {
        int p = blockIdx.y * 2 + pp;
        __syncthreads();   // As ready / prev path's MFMA reads done
        const ushort_t* Wp = Wt + ((size_t)p << 15);
#pragma unroll
        for (int c = 0; c < 8; ++c) {
            int kb = c * 32 + half;
            const ushort_t* bp = Wp + (size_t)srow * IN_F + kb;
            *(uint4*)&Bs[srow * AP + kb]     = *(const uint4*)(bp);
            *(uint4*)&Bs[srow * AP + kb + 8] = *(const uint4*)(bp + 8);
        }
        __syncthreads();
        f32x4 acc[4][4] = {};
#pragma unroll
        for (int k0 = 0; k0 < IN_F; k0 += 32) {
            s16x8 aF[4], bF[4];
            int kk = k0 + (lane >> 4) * 8;
#pragma unroll
            for (int m = 0; m < 4; ++m)
                aF[m] = *(const s16x8*)&As[(wr * 64 + m * 16 + (lane & 15)) * AP + kk];
#pragma unroll
            for (int n = 0; n < 4; ++n)
                bF[n] = *(const s16x8*)&Bs[(wc * 64 + n * 16 + (lane & 15)) * AP + kk];
#pragma unroll
            for (int m = 0; m < 4; ++m)
#pragma unroll
                for (int n = 0; n < 4; ++n)
                    acc[m][n] = __builtin_amdgcn_mfma_f32_16x16x32_bf16(aF[m], bF[n], acc[m][n], 0, 0, 0);
        }
        ushort_t* xp = xwb + (size_t)p * N_NODES * OUT_F;
        const float* rp = rsout + (size_t)p * N_NODES;
#pragma unroll
        for (int m = 0; m < 4; ++m) {
#pragma unroll
            for (int i = 0; i < 4; ++i) {
                int row = m0 + wr * 64 + m * 16 + (lane >> 4) * 4 + i;
                if (row < N_NODES) {
                    float rs = rp[row];
#pragma unroll
                    for (int n = 0; n < 4; ++n) {
                        int col = wc * 64 + n * 16 + (lane & 15);
                        xp[(size_t)row * OUT_F + col] = f2bf(acc[m][n][i] * rs);
                    }
                }
            }
        }
    }
}

// ---------------- gather: 2 nodes per wave, interleaved chains; h(bf16) = agg*rsqrt(deg)+b_conv ----------------
__global__ __launch_bounds__(256) void gather_kernel(const ushort_t* __restrict__ xwb,
                                                     const ushort_t* __restrict__ eidx2,
                                                     const int* __restrict__ rsn,
                                                     const float* __restrict__ bconv,
                                                     uint_t* __restrict__ hb)   // u32 view (2×bf16)
{
    int wid = threadIdx.x >> 6, lane = threadIdx.x & 63;
    int p = blockIdx.y;
    int n0 = (blockIdx.x * 4 + wid) * 2;
    const int* rsn_p = rsn + (size_t)p * (N_NODES + 1);
    const ushort_t* eidx2_p = eidx2 + (size_t)p * E_EDGES;
    int bA = rsn_p[n0], mid = rsn_p[n0 + 1], eB = rsn_p[n0 + 2];
    const uint_t* base = (const uint_t*)xwb + (size_t)p * N_NODES * 64 + lane;
    float a0 = 0.f, a1 = 0.f, b0 = 0.f, b1 = 0.f;
    int iA = bA, iB = mid;
    // interleaved unroll-4 on both node chains -> 8 outstanding row loads
    while (iA + 4 <= mid && iB + 4 <= eB) {
        int sA0 = eidx2_p[iA], sA1 = eidx2_p[iA + 1], sA2 = eidx2_p[iA + 2], sA3 = eidx2_p[iA + 3];
        int sB0 = eidx2_p[iB], sB1 = eidx2_p[iB + 1], sB2 = eidx2_p[iB + 2], sB3 = eidx2_p[iB + 3];
        uint_t wA0 = base[(size_t)sA0 * 64];
        uint_t wA1 = base[(size_t)sA1 * 64];
        uint_t wA2 = base[(size_t)sA2 * 64];
        uint_t wA3 = base[(size_t)sA3 * 64];
        uint_t wB0 = base[(size_t)sB0 * 64];
        uint_t wB1 = base[(size_t)sB1 * 64];
        uint_t wB2 = base[(size_t)sB2 * 64];
        uint_t wB3 = base[(size_t)sB3 * 64];
        a0 += (bf2f((ushort_t)wA0) + bf2f((ushort_t)wA1)) + (bf2f((ushort_t)wA2) + bf2f((ushort_t)wA3));
        a1 += (bf2f((ushort_t)(wA0 >> 16)) + bf2f((ushort_t)(wA1 >> 16))) +
              (bf2f((ushort_t)(wA2 >> 16)) + bf2f((ushort_t)(wA3 >> 16)));
        b0 += (bf2f((ushort_t)wB0) + bf2f((ushort_t)wB1)) + (bf2f((ushort_t)wB2) + bf2f((ushort_t)wB3));
        b1 += (bf2f((ushort_t)(wB0 >> 16)) + bf2f((ushort_t)(wB1 >> 16))) +
              (bf2f((ushort_t)(wB2 >> 16)) + bf2f((ushort_t)(wB3 >> 16)));
        iA += 4; iB += 4;
    }
    for (; iA + 4 <= mid; iA += 4) {
        int s0 = eidx2_p[iA], s1 = eidx2_p[iA + 1], s2 = eidx2_p[iA + 2], s3 = eidx2_p[iA + 3];
        uint_t w0 = base[(size_t)s0 * 64];
        uint_t w1 = base[(size_t)s1 * 64];
        uint_t w2 = base[(size_t)s2 * 64];
        uint_t w3 = base[(size_t)s3 * 64];
        a0 += (bf2f((ushort_t)w0) + bf2f((ushort_t)w1)) + (bf2f((ushort_t)w2) + bf2f((ushort_t)w3));
        a1 += (bf2f((ushort_t)(w0 >> 16)) + bf2f((ushort_t)(w1 >> 16))) +
              (bf2f((ushort_t)(w2 >> 16)) + bf2f((ushort_t)(w3 >> 16)));
    }
    for (; iA < mid; ++iA) {
        uint_t w = base[(size_t)eidx2_p[iA] * 64];
        a0 += bf2f((ushort_t)w);
        a1 += bf2f((ushort_t)(w >> 16));
    }
    for (; iB + 4 <= eB; iB += 4) {
        int s0 = eidx2_p[iB], s1 = eidx2_p[iB + 1], s2 = eidx2_p[iB + 2], s3 = eidx2_p[iB + 3];
        uint_t w0 = base[(size_t)s0 * 64];
        uint_t w1 = base[(size_t)s1 * 64];
        uint_t w2 = base[(size_t)s2 * 64];
        uint_t w3 = base[(size_t)s3 * 64];
        b0 += (bf2f((ushort_t)w0) + bf2f((ushort_t)w1)) + (bf2f((ushort_t)w2) + bf2f((ushort_t)w3));
        b1 += (bf2f((ushort_t)(w0 >> 16)) + bf2f((ushort_t)(w1 >> 16))) +
              (bf2f((ushort_t)(w2 >> 16)) + bf2f((ushort_t)(w3 >> 16)));
    }
    for (; iB < eB; ++iB) {
        uint_t w = base[(size_t)eidx2_p[iB] * 64];
        b0 += bf2f((ushort_t)w);
        b1 += bf2f((ushort_t)(w >> 16));
    }
    int dA = mid - bA, dB = eB - mid;
    float scA = rsqrtf((float)(dA > 0 ? dA : 1));
    float scB = rsqrtf((float)(dB > 0 ? dB : 1));
    float2 bc = *(const float2*)(bconv + (size_t)p * OUT_F + 2 * lane);
    hb[((size_t)p * N_NODES + n0) * 64 + lane] =
        (uint_t)f2bf(fmaf(a0, scA, bc.x)) | ((uint_t)f2bf(fmaf(a1, scA, bc.y)) << 16);
    hb[((size_t)p * N_NODES + n0 + 1) * 64 + lane] =
        (uint_t)f2bf(fmaf(b0, scB, bc.x)) | ((uint_t)f2bf(fmaf(b1, scB, bc.y)) << 16);
}

// ---------------- MFMA fc (bf16 h in) + tanh + per-block column sums, all paths ----------------
__global__ __launch_bounds__(256) void fc_mfma_kernel(const ushort_t* __restrict__ hb,
                                                      const ushort_t* __restrict__ fcwb,
                                                      const float* __restrict__ fcb,
                                                      float* __restrict__ partial)
{
    __shared__ ushort_t As[128 * FP];   // 34 KB
    __shared__ ushort_t Bs[128 * FP];
    __shared__ float red[2][128];
    int m0 = blockIdx.x * 128;
    int p = blockIdx.y;
    int t = threadIdx.x;
    int wid = t >> 6, lane = t & 63;
    int wr = wid >> 1, wc = wid & 1;
    int srow = t >> 1, half = (t & 1) * 16;
    int gr = m0 + srow;
    const ushort_t* hp = hb + (size_t)p * N_NODES * OUT_F;
#pragma unroll
    for (int c = 0; c < 4; ++c) {
        int kb = c * 32 + half;
        uint4 w0 = make_uint4(0, 0, 0, 0), w1 = make_uint4(0, 0, 0, 0);
        if (gr < N_NODES) {
            const ushort_t* ap = hp + (size_t)gr * OUT_F + kb;
            w0 = *(const uint4*)(ap);
            w1 = *(const uint4*)(ap + 8);
        }
        *(uint4*)&As[srow * FP + kb]     = w0;
        *(uint4*)&As[srow * FP + kb + 8] = w1;
        const ushort_t* bp = fcwb + (size_t)srow * OUT_F + kb;
        *(uint4*)&Bs[srow * FP + kb]     = *(const uint4*)(bp);
        *(uint4*)&Bs[srow * FP + kb + 8] = *(const uint4*)(bp + 8);
    }
    __syncthreads();
    f32x4 acc[4][4] = {};
#pragma unroll
    for (int k0 = 0; k0 < OUT_F; k0 += 32) {
        s16x8 aF[4], bF[4];
        int kk = k0 + (lane >> 4) * 8;
#pragma unroll
        for (int m = 0; m < 4; ++m)
            aF[m] = *(const s16x8*)&As[(wr * 64 + m * 16 + (lane & 15)) * FP + kk];
#pragma unroll
        for (int n = 0; n < 4; ++n)
            bF[n] = *(const s16x8*)&Bs[(wc * 64 + n * 16 + (lane & 15)) * FP + kk];
#pragma unroll
        for (int m = 0; m < 4; ++m)
#pragma unroll
            for (int n = 0; n < 4; ++n)
                acc[m][n] = __builtin_amdgcn_mfma_f32_16x16x32_bf16(aF[m], bF[n], acc[m][n], 0, 0, 0);
    }
#pragma unroll
    for (int n = 0; n < 4; ++n) {
        int col = wc * 64 + n * 16 + (lane & 15);
        float fb = fcb[col];
        float s = 0.f;
#pragma unroll
        for (int m = 0; m < 4; ++m)
#pragma unroll
            for (int i = 0; i < 4; ++i) {
                int row = m0 + wr * 64 + m * 16 + (lane >> 4) * 4 + i;
                if (row < N_NODES) s += tanhf(acc[m][n][i] + fb);
            }
        s += __shfl_xor(s, 16);
        s += __shfl_xor(s, 32);
        if (lane < 16) red[wr][col] = s;
    }
    __syncthreads();
    if (t < 128)
        partial[((size_t)p * GBLK + blockIdx.x) * OUT_F + t] = red[0][t] + red[1][t];
}

// ---------------- reduce partials -> sp -> beta softmax ----------------
__global__ __launch_bounds__(512) void beta_reduce_kernel(const float* __restrict__ partial,
                                                          const float* __restrict__ att,
                                                          float* __restrict__ beta)
{
    int t = threadIdx.x;          // 512 = P*128
    int p = t >> 7, c = t & 127;
    float s = 0.f;
    for (int i = 0; i < GBLK; ++i)
        s += partial[((size_t)p * GBLK + i) * OUT_F + c];
    float v = att[p * OUT_F + c] * (s * (1.0f / N_NODES));
    __shared__ float red[512];
    red[t] = v;
    __syncthreads();
    for (int off = 64; off >= 1; off >>= 1) {
        if (c < off) red[t] += red[t + off];
        __syncthreads();
    }
    if (t == 0) {
        float w[P_PATHS], mx = -1e30f;
        for (int q = 0; q < P_PATHS; ++q) { w[q] = red[q * 128]; mx = fmaxf(mx, w[q]); }
        float sum = 0.f;
        for (int q = 0; q < P_PATHS; ++q) { w[q] = expf(w[q] - mx); sum += w[q]; }
        for (int q = 0; q < P_PATHS; ++q) beta[q] = w[q] / sum;
    }
}

// ---------------- out = sum_p beta[p]*h[p] + h_bias ----------------
__global__ void combine_kernel(const uint_t* __restrict__ hb, const float* __restrict__ hbias,
                               const float* __restrict__ beta, float* __restrict__ out)
{
    int idx = blockIdx.x * blockDim.x + threadIdx.x;   // over N*64
    if (idx >= N_NODES * 64) return;
    int n = idx >> 6;
    int w = idx & 63;
    float2 hbv = *(const float2*)(hbias + 2 * w);
    float r0 = hbv.x, r1 = hbv.y;
#pragma unroll
    for (int p = 0; p < P_PATHS; ++p) {
        float bp = beta[p];
        uint_t v = hb[((size_t)p * N_NODES + n) * 64 + w];
        r0 = fmaf(bp, bf2f((ushort_t)v), r0);
        r1 = fmaf(bp, bf2f((ushort_t)(v >> 16)), r1);
    }
    *(float2*)(out + (size_t)n * OUT_F + 2 * w) = make_float2(r0, r1);
}

extern "C" void kernel_launch(void* const* d_in, const int* in_sizes, int n_in,
                              void* d_out, int out_size, void* d_ws, size_t ws_size,
                              hipStream_t stream)
{
    const float* x      = (const float*)d_in[0];
    const float* W      = (const float*)d_in[1];
    const float* b_conv = (const float*)d_in[2];
    const float* att    = (const float*)d_in[3];
    const float* fc_w   = (const float*)d_in[4];
    const float* fc_b   = (const float*)d_in[5];
    const float* h_bias = (const float*)d_in[6];
    const int*   src    = (const int*)d_in[7];
    const int*   dst    = (const int*)d_in[8];
    float* out = (float*)d_out;
    float* ws  = (float*)d_ws;

    // ---- ws layout, total ~132.3 MB ----
    size_t off_rsout   = 0;                                            // P*N f32
    size_t off_partial = off_rsout + (size_t)P_PATHS * N_NODES;        // P*GBLK*128 f32
    size_t off_beta    = off_partial + (size_t)P_PATHS * GBLK * OUT_F;
    size_t off_i32     = (off_beta + 4 + 63) & ~(size_t)63;
    // int region (units of int)
    size_t i_bstart  = 0;                                  // P*NBUCK+1 -> pad 1600
    size_t i_bcursor = 1600;                               // P*NBUCK   -> pad 1600
    size_t i_bcounts = 3200;                               // P*NBUCK   -> pad 1600
    size_t i_rsn     = 4800;                               // P*(N+1) = 200004 -> pad 200064
    size_t i_dhist   = 204864;                             // P*QTR*DSL*Q_W = 2,000,000
    size_t i_ebuf    = i_dhist + (size_t)P_PATHS * QTR * DSL * Q_W;   // P*E
    size_t n_ints    = i_ebuf + (size_t)P_PATHS * E_EDGES;
    size_t off_u16   = off_i32 + ((n_ints + 63) & ~(size_t)63);
    // ushort region (units of ushort)
    size_t u_hb    = 0;                                    // P*N*128
    size_t u_xwb   = u_hb + (size_t)P_PATHS * N_NODES * OUT_F;   // P*N*128
    size_t u_eidx2 = u_xwb + (size_t)P_PATHS * N_NODES * OUT_F;  // P*E
    size_t u_Wt    = u_eidx2 + (size_t)P_PATHS * E_EDGES;        // P*IN*OUT
    size_t u_fcwb  = u_Wt + (size_t)P_PATHS * IN_F * OUT_F;      // OUT*OUT

    float* rsout   = ws + off_rsout;
    float* partial = ws + off_partial;
    float* beta    = ws + off_beta;
    int*   ibase   = (int*)(ws + off_i32);
    int*    bstart  = ibase + i_bstart;
    int*    bcursor = ibase + i_bcursor;
    uint_t* bcounts = (uint_t*)(ibase + i_bcounts);
    int*    rsn     = ibase + i_rsn;
    uint_t* dhist   = (uint_t*)(ibase + i_dhist);
    uint_t* ebuf    = (uint_t*)(ibase + i_ebuf);
    ushort_t* ubase = (ushort_t*)(ws + off_u16);
    ushort_t* hb    = ubase + u_hb;
    ushort_t* xwb   = ubase + u_xwb;
    ushort_t* eidx2 = ubase + u_eidx2;
    ushort_t* Wt    = ubase + u_Wt;
    ushort_t* fcwb  = ubase + u_fcwb;

    // only bucket counters accumulate -> zero each call
    hipMemsetAsync(bcounts, 0, (size_t)P_PATHS * NBUCK * sizeof(uint_t), stream);

    prep_kernel<<<(P_PATHS * IN_F * OUT_F + 255) / 256, 256, 0, stream>>>(W, fc_w, Wt, fcwb);
    deghist_kernel<<<dim3(DSL, QTR + 1, P_PATHS), 256, 0, stream>>>(src, dst, dhist, bcounts);
    rsout_bscan_kernel<<<RSB + 1, 1024, 0, stream>>>(dhist, rsout, bcounts, bstart, bcursor);

    gemm_xall_kernel<<<dim3(GBLK, 2), 256, 0, stream>>>(x, Wt, rsout, xwb);
    bscatter_kernel<<<dim3(NCHUNK, P_PATHS), 256, 0, stream>>>(src, dst, bcursor, ebuf);
    blocal_kernel<<<dim3(NBUCK, P_PATHS), 256, 0, stream>>>(ebuf, bstart, eidx2, rsn);
    gather_kernel<<<dim3(N_NODES / 8, P_PATHS), 256, 0, stream>>>(
        xwb, eidx2, rsn, b_conv, (uint_t*)hb);
    fc_mfma_kernel<<<dim3(GBLK, P_PATHS), 256, 0, stream>>>(hb, fcwb, fc_b, partial);

    beta_reduce_kernel<<<1, 512, 0, stream>>>(partial, att, beta);
    combine_kernel<<<(N_NODES * 64 + 255) / 256, 256, 0, stream>>>(
        (const uint_t*)hb, h_bias, beta, out);
}

// Round 9
// 316.569 us; speedup vs baseline: 10.3608x; 1.0463x over previous
//
#include <hip/hip_runtime.h>
#include <math.h>

#define N_NODES 50000
#define P_PATHS 4
#define E_EDGES 800000
#define IN_F 256
#define OUT_F 128
#define NPB 128                        // nodes per bucket
#define NBUCK 391                      // ceil(N/NPB)
#define NCHUNK 200                     // edge chunks per path
#define CHUNK_E (E_EDGES / NCHUNK)     // 4000
#define GBLK 391                       // row-blocks for gemm/fc (128 rows each)
#define DSL 20                         // edge slices for deg-out histogram
#define QTR 4                          // node quarters
#define Q_N 12500                      // nodes per quarter
#define Q_W 6250                       // packed u32 words per quarter (25KB LDS)
#define BKP 72                         // LDS pitch (u16) for BK=64 gemm tiles
#define FP 136                         // LDS pitch (u16) for K=128 tiles
#define RSB 196                        // rsout blocks in merged rsout+bscan

typedef unsigned short ushort_t;
typedef unsigned int uint_t;
typedef float f32x4 __attribute__((ext_vector_type(4)));
typedef short s16x8 __attribute__((ext_vector_type(8)));

__device__ __forceinline__ ushort_t f2bf(float f) {
    uint_t u = __float_as_uint(f);
    return (ushort_t)((u + 0x7FFFu + ((u >> 16) & 1u)) >> 16);   // RNE
}
__device__ __forceinline__ float bf2f(ushort_t h) {
    return __uint_as_float(((uint_t)h) << 16);
}
__device__ __forceinline__ uint4 pack8(const float4 f0, const float4 f1) {
    uint4 w;
    w.x = (uint_t)f2bf(f0.x) | ((uint_t)f2bf(f0.y) << 16);
    w.y = (uint_t)f2bf(f0.z) | ((uint_t)f2bf(f0.w) << 16);
    w.z = (uint_t)f2bf(f1.x) | ((uint_t)f2bf(f1.y) << 16);
    w.w = (uint_t)f2bf(f1.z) | ((uint_t)f2bf(f1.w) << 16);
    return w;
}
__device__ __forceinline__ float fast_tanh(float v) {
    v = fminf(fmaxf(v, -20.f), 20.f);
    float ex = __expf(2.f * v);
    return (ex - 1.f) / (ex + 1.f);
}
__device__ __forceinline__ void acc4(float4& a, uint2 w) {
    a.x += bf2f((ushort_t)w.x);
    a.y += bf2f((ushort_t)(w.x >> 16));
    a.z += bf2f((ushort_t)w.y);
    a.w += bf2f((ushort_t)(w.y >> 16));
}

// ---------------- prep: W -> Wt bf16 (transposed [p][n][k]), fc_w -> bf16 ----------------
__global__ void prep_kernel(const float* __restrict__ W, const float* __restrict__ fcw,
                            ushort_t* __restrict__ Wt, ushort_t* __restrict__ fcwb)
{
    int idx = blockIdx.x * blockDim.x + threadIdx.x;
    if (idx < P_PATHS * IN_F * OUT_F) {          // 131072
        int p = idx >> 15;
        int r = idx & 32767;
        int k = r >> 7;
        int n = r & 127;
        Wt[((size_t)p << 15) + (size_t)n * IN_F + k] = f2bf(W[idx]);
    }
    if (idx < OUT_F * OUT_F) fcwb[idx] = f2bf(fcw[idx]);
}

// ---------------- deg_out hist (q<QTR) + dst bucket hist (q==QTR), per edge slice ----------------
__global__ __launch_bounds__(256) void deghist_kernel(const int* __restrict__ src,
                                                      const int* __restrict__ dst,
                                                      uint_t* __restrict__ dhist,
                                                      uint_t* __restrict__ bcounts)
{
    __shared__ uint_t cnt[Q_W];   // 25 KB
    int sl = blockIdx.x, q = blockIdx.y, p = blockIdx.z;
    int t = threadIdx.x;
    if (q == QTR) {
        for (int i = t; i < NBUCK; i += 256) cnt[i] = 0;
        __syncthreads();
        const int4* d4 = (const int4*)(dst + (size_t)p * E_EDGES + (size_t)sl * (E_EDGES / DSL));
        for (int i = t; i < E_EDGES / DSL / 4; i += 256) {
            int4 v = d4[i];
            atomicAdd(&cnt[v.x >> 7], 1u);
            atomicAdd(&cnt[v.y >> 7], 1u);
            atomicAdd(&cnt[v.z >> 7], 1u);
            atomicAdd(&cnt[v.w >> 7], 1u);
        }
        __syncthreads();
        for (int i = t; i < NBUCK; i += 256)
            if (cnt[i]) atomicAdd(&bcounts[p * NBUCK + i], cnt[i]);
        return;
    }
    int nbase = q * Q_N;
    for (int i = t; i < Q_W; i += 256) cnt[i] = 0;
    __syncthreads();
    const int4* s4 = (const int4*)(src + (size_t)p * E_EDGES + (size_t)sl * (E_EDGES / DSL));
    for (int i = t; i < E_EDGES / DSL / 4; i += 256) {
        int4 v = s4[i];
        uint_t r;
        r = (uint_t)(v.x - nbase); if (r < Q_N) atomicAdd(&cnt[r >> 1], 1u << ((r & 1) * 16));
        r = (uint_t)(v.y - nbase); if (r < Q_N) atomicAdd(&cnt[r >> 1], 1u << ((r & 1) * 16));
        r = (uint_t)(v.z - nbase); if (r < Q_N) atomicAdd(&cnt[r >> 1], 1u << ((r & 1) * 16));
        r = (uint_t)(v.w - nbase); if (r < Q_N) atomicAdd(&cnt[r >> 1], 1u << ((r & 1) * 16));
    }
    __syncthreads();
    uint_t* outp = dhist + (((size_t)p * QTR + q) * DSL + sl) * Q_W;
    for (int i = t; i < Q_W; i += 256) outp[i] = cnt[i];
}

// ---------------- merged: blocks 0..RSB-1 -> rsout; block RSB -> bucket scan ----------------
__global__ __launch_bounds__(1024) void rsout_bscan_kernel(const uint_t* __restrict__ dhist,
                                                           float* __restrict__ rsout,
                                                           const uint_t* __restrict__ bcounts,
                                                           int* __restrict__ bstart,
                                                           int* __restrict__ bcursor)
{
    int t = threadIdx.x;
    if (blockIdx.x == RSB) {
        __shared__ int a[2048], b[2048];
        for (int i = t; i < 2048; i += 1024)
            a[i] = (i < P_PATHS * NBUCK) ? (int)bcounts[i] : 0;
        __syncthreads();
        int* pin = a; int* pout = b;
        for (int off = 1; off < 2048; off <<= 1) {
            for (int i = t; i < 2048; i += 1024)
                pout[i] = pin[i] + (i >= off ? pin[i - off] : 0);
            __syncthreads();
            int* tmp = pin; pin = pout; pout = tmp;
        }
        for (int i = t; i < P_PATHS * NBUCK; i += 1024) {
            int st = pin[i] - (int)bcounts[i];
            bstart[i] = st;
            bcursor[i] = st;
        }
        if (t == 0) bstart[P_PATHS * NBUCK] = pin[P_PATHS * NBUCK - 1];
        return;
    }
    int idx = blockIdx.x * 1024 + t;      // over P*QTR*Q_W
    if (idx >= P_PATHS * QTR * Q_W) return;
    int ph = idx / Q_W;
    int w  = idx % Q_W;
    const uint_t* base = dhist + (size_t)ph * DSL * Q_W + w;
    uint_t s = 0;
#pragma unroll
    for (int sl = 0; sl < DSL; ++sl) s += base[(size_t)sl * Q_W];
    int p = ph >> 2, q = ph & 3;
    int node = q * Q_N + 2 * w;
    uint_t c0 = s & 0xFFFFu, c1 = s >> 16;
    rsout[(size_t)p * N_NODES + node]     = rsqrtf((float)(c0 ? c0 : 1u));
    rsout[(size_t)p * N_NODES + node + 1] = rsqrtf((float)(c1 ? c1 : 1u));
}

// ---------------- scatter packed edges (src | dloc<<16) into bucket order, all paths ----------------
__global__ __launch_bounds__(256) void bscatter_kernel(const int* __restrict__ src,
                                                       const int* __restrict__ dst,
                                                       int* __restrict__ bcursor,
                                                       uint_t* __restrict__ ebuf)
{
    __shared__ uint_t bh[NBUCK];
    __shared__ uint_t lbase[NBUCK];
    int p = blockIdx.y;
    int t = threadIdx.x;
    int sub = p * E_EDGES;
    int* bcursor_p = bcursor + p * NBUCK;
    uint_t* ebuf_p = ebuf + (size_t)p * E_EDGES;
    for (int i = t; i < NBUCK; i += 256) bh[i] = 0;
    __syncthreads();
    size_t ebase = (size_t)p * E_EDGES + (size_t)blockIdx.x * CHUNK_E;
    const int4* d4 = (const int4*)(dst + ebase);
    const int4* s4 = (const int4*)(src + ebase);
    for (int i = t; i < CHUNK_E / 4; i += 256) {
        int4 v = d4[i];
        atomicAdd(&bh[v.x >> 7], 1u);
        atomicAdd(&bh[v.y >> 7], 1u);
        atomicAdd(&bh[v.z >> 7], 1u);
        atomicAdd(&bh[v.w >> 7], 1u);
    }
    __syncthreads();
    for (int i = t; i < NBUCK; i += 256) {
        uint_t c = bh[i];
        lbase[i] = c ? (uint_t)(atomicAdd(&bcursor_p[i], (int)c) - sub) : 0u;
        bh[i] = 0;     // reuse as local cursor
    }
    __syncthreads();
    for (int i = t; i < CHUNK_E / 4; i += 256) {
        int4 d = d4[i];
        int4 s = s4[i];
        { int bk = d.x >> 7; uint_t pos = lbase[bk] + atomicAdd(&bh[bk], 1u); ebuf_p[pos] = (uint_t)s.x | ((uint_t)(d.x & 127) << 16); }
        { int bk = d.y >> 7; uint_t pos = lbase[bk] + atomicAdd(&bh[bk], 1u); ebuf_p[pos] = (uint_t)s.y | ((uint_t)(d.y & 127) << 16); }
        { int bk = d.z >> 7; uint_t pos = lbase[bk] + atomicAdd(&bh[bk], 1u); ebuf_p[pos] = (uint_t)s.z | ((uint_t)(d.z & 127) << 16); }
        { int bk = d.w >> 7; uint_t pos = lbase[bk] + atomicAdd(&bh[bk], 1u); ebuf_p[pos] = (uint_t)s.w | ((uint_t)(d.w & 127) << 16); }
    }
}

// ---------------- per-bucket local CSR build, all paths ----------------
__global__ __launch_bounds__(256) void blocal_kernel(const uint_t* __restrict__ ebuf,
                                                     const int* __restrict__ bstart,
                                                     ushort_t* __restrict__ eidx2,
                                                     int* __restrict__ rsn)
{
    __shared__ uint_t hist[NPB];
    __shared__ uint_t cur[NPB];
    __shared__ uint_t sa[NPB], sb[NPB];
    int bkt = blockIdx.x;
    int p = blockIdx.y;
    int t = threadIdx.x;
    int sub = p * E_EDGES;
    const uint_t* ebuf_p = ebuf + (size_t)p * E_EDGES;
    ushort_t* eidx2_p = eidx2 + (size_t)p * E_EDGES;
    int* rsn_p = rsn + (size_t)p * (N_NODES + 1);
    if (t < NPB) hist[t] = 0;
    __syncthreads();
    int r0 = bstart[p * NBUCK + bkt] - sub;
    int r1 = bstart[p * NBUCK + bkt + 1] - sub;
    for (int e = r0 + t; e < r1; e += 256)
        atomicAdd(&hist[ebuf_p[e] >> 16], 1u);
    __syncthreads();
    if (t < NPB) sa[t] = hist[t];
    __syncthreads();
    uint_t* pin = sa; uint_t* pout = sb;
    for (int off = 1; off < NPB; off <<= 1) {
        if (t < NPB) pout[t] = pin[t] + (t >= off ? pin[t - off] : 0u);
        __syncthreads();
        uint_t* tmp = pin; pin = pout; pout = tmp;
    }
    if (t < NPB) {
        uint_t ex = pin[t] - hist[t];
        int node = bkt * NPB + t;
        if (node < N_NODES) rsn_p[node] = r0 + (int)ex;
        cur[t] = ex;
    }
    if (bkt == NBUCK - 1 && t == 0) rsn_p[N_NODES] = r1;   // == E_EDGES
    __syncthreads();
    for (int e = r0 + t; e < r1; e += 256) {
        uint_t pk = ebuf_p[e];
        int dl = (int)(pk >> 16);
        uint_t pos = atomicAdd(&cur[dl], 1u);
        eidx2_p[r0 + pos] = (ushort_t)(pk & 0xFFFFu);
    }
}

// ---------------- MFMA GEMM, BK=64 tiles, path-pair per block ----------------
__global__ __launch_bounds__(256) void gemm_xall_kernel(const float* __restrict__ x,
                                                        const ushort_t* __restrict__ Wt,
                                                        const float* __restrict__ rsout,
                                                        ushort_t* __restrict__ xwb)
{
    __shared__ ushort_t As[128 * BKP];   // 18.4 KB
    __shared__ ushort_t Bs[128 * BKP];   // 18.4 KB
    int m0 = blockIdx.x * 128;
    int t = threadIdx.x;
    int wid = t >> 6, lane = t & 63;
    int wr = wid >> 1, wc = wid & 1;
    int srow = t >> 1, h32 = (t & 1) * 32;
    int gr = m0 + srow;
    for (int pp = 0; pp < 2; ++pp) {
        int p = blockIdx.y * 2 + pp;
        const ushort_t* Wp = Wt + ((size_t)p << 15);
        f32x4 acc[4][4] = {};
        for (int kt = 0; kt < 4; ++kt) {
            __syncthreads();   // prior tile reads done
            {   // A: 128x64 fp32 -> bf16
                const float* ap = x + (size_t)gr * IN_F + kt * 64 + h32;
#pragma unroll
                for (int c = 0; c < 4; ++c) {
                    float4 f0 = make_float4(0.f, 0.f, 0.f, 0.f), f1 = f0;
                    if (gr < N_NODES) {
                        f0 = *(const float4*)(ap + c * 8);
                        f1 = *(const float4*)(ap + c * 8 + 4);
                    }
                    *(uint4*)&As[srow * BKP + h32 + c * 8] = pack8(f0, f1);
                }
            }
            {   // B: Wt rows direct u16 copy
                const ushort_t* bp = Wp + (size_t)srow * IN_F + kt * 64 + h32;
#pragma unroll
                for (int c = 0; c < 4; ++c)
                    *(uint4*)&Bs[srow * BKP + h32 + c * 8] = *(const uint4*)(bp + c * 8);
            }
            __syncthreads();
#pragma unroll
            for (int k0 = 0; k0 < 64; k0 += 32) {
                s16x8 aF[4], bF[4];
                int kk = k0 + (lane >> 4) * 8;
#pragma unroll
                for (int m = 0; m < 4; ++m)
                    aF[m] = *(const s16x8*)&As[(wr * 64 + m * 16 + (lane & 15)) * BKP + kk];
#pragma unroll
                for (int n = 0; n < 4; ++n)
                    bF[n] = *(const s16x8*)&Bs[(wc * 64 + n * 16 + (lane & 15)) * BKP + kk];
#pragma unroll
                for (int m = 0; m < 4; ++m)
#pragma unroll
                    for (int n = 0; n < 4; ++n)
                        acc[m][n] = __builtin_amdgcn_mfma_f32_16x16x32_bf16(aF[m], bF[n], acc[m][n], 0, 0, 0);
            }
        }
        ushort_t* xp = xwb + (size_t)p * N_NODES * OUT_F;
        const float* rp = rsout + (size_t)p * N_NODES;
#pragma unroll
        for (int m = 0; m < 4; ++m) {
#pragma unroll
            for (int i = 0; i < 4; ++i) {
                int row = m0 + wr * 64 + m * 16 + (lane >> 4) * 4 + i;
                if (row < N_NODES) {
                    float rs = rp[row];
#pragma unroll
                    for (int n = 0; n < 4; ++n) {
                        int col = wc * 64 + n * 16 + (lane & 15);
                        xp[(size_t)row * OUT_F + col] = f2bf(acc[m][n][i] * rs);
                    }
                }
            }
        }
    }
}

// ---------------- gather: half-wave per node, u64 row loads, 2-node interleave ----------------
__global__ __launch_bounds__(256) void gather_kernel(const ushort_t* __restrict__ xwb,
                                                     const ushort_t* __restrict__ eidx2,
                                                     const int* __restrict__ rsn,
                                                     const float* __restrict__ bconv,
                                                     uint2* __restrict__ hb)   // row = 32 uint2
{
    int hw = threadIdx.x >> 5;          // half-wave 0..7
    int lane = threadIdx.x & 31;        // cols 4*lane .. 4*lane+3
    int p = blockIdx.y;
    int n0 = (blockIdx.x * 8 + hw) * 2;
    const int* rsn_p = rsn + (size_t)p * (N_NODES + 1);
    const ushort_t* eidx2_p = eidx2 + (size_t)p * E_EDGES;
    int bA = rsn_p[n0], mid = rsn_p[n0 + 1], eB = rsn_p[n0 + 2];
    const uint2* base = (const uint2*)xwb + (size_t)p * N_NODES * 32 + lane;
    float4 aA = make_float4(0.f, 0.f, 0.f, 0.f);
    float4 aB = make_float4(0.f, 0.f, 0.f, 0.f);
    int iA = bA, iB = mid;
    while (iA + 4 <= mid && iB + 4 <= eB) {
        int sA0 = eidx2_p[iA], sA1 = eidx2_p[iA + 1], sA2 = eidx2_p[iA + 2], sA3 = eidx2_p[iA + 3];
        int sB0 = eidx2_p[iB], sB1 = eidx2_p[iB + 1], sB2 = eidx2_p[iB + 2], sB3 = eidx2_p[iB + 3];
        uint2 wA0 = base[(size_t)sA0 * 32];
        uint2 wA1 = base[(size_t)sA1 * 32];
        uint2 wA2 = base[(size_t)sA2 * 32];
        uint2 wA3 = base[(size_t)sA3 * 32];
        uint2 wB0 = base[(size_t)sB0 * 32];
        uint2 wB1 = base[(size_t)sB1 * 32];
        uint2 wB2 = base[(size_t)sB2 * 32];
        uint2 wB3 = base[(size_t)sB3 * 32];
        acc4(aA, wA0); acc4(aA, wA1); acc4(aA, wA2); acc4(aA, wA3);
        acc4(aB, wB0); acc4(aB, wB1); acc4(aB, wB2); acc4(aB, wB3);
        iA += 4; iB += 4;
    }
    for (; iA + 4 <= mid; iA += 4) {
        int s0 = eidx2_p[iA], s1 = eidx2_p[iA + 1], s2 = eidx2_p[iA + 2], s3 = eidx2_p[iA + 3];
        uint2 w0 = base[(size_t)s0 * 32];
        uint2 w1 = base[(size_t)s1 * 32];
        uint2 w2 = base[(size_t)s2 * 32];
        uint2 w3 = base[(size_t)s3 * 32];
        acc4(aA, w0); acc4(aA, w1); acc4(aA, w2); acc4(aA, w3);
    }
    for (; iA < mid; ++iA) {
        uint2 w = base[(size_t)eidx2_p[iA] * 32];
        acc4(aA, w);
    }
    for (; iB + 4 <= eB; iB += 4) {
        int s0 = eidx2_p[iB], s1 = eidx2_p[iB + 1], s2 = eidx2_p[iB + 2], s3 = eidx2_p[iB + 3];
        uint2 w0 = base[(size_t)s0 * 32];
        uint2 w1 = base[(size_t)s1 * 32];
        uint2 w2 = base[(size_t)s2 * 32];
        uint2 w3 = base[(size_t)s3 * 32];
        acc4(aB, w0); acc4(aB, w1); acc4(aB, w2); acc4(aB, w3);
    }
    for (; iB < eB; ++iB) {
        uint2 w = base[(size_t)eidx2_p[iB] * 32];
        acc4(aB, w);
    }
    int dA = mid - bA, dB = eB - mid;
    float scA = rsqrtf((float)(dA > 0 ? dA : 1));
    float scB = rsqrtf((float)(dB > 0 ? dB : 1));
    float4 bc = *(const float4*)(bconv + (size_t)p * OUT_F + lane * 4);
    uint2 oA, oB;
    oA.x = (uint_t)f2bf(fmaf(aA.x, scA, bc.x)) | ((uint_t)f2bf(fmaf(aA.y, scA, bc.y)) << 16);
    oA.y = (uint_t)f2bf(fmaf(aA.z, scA, bc.z)) | ((uint_t)f2bf(fmaf(aA.w, scA, bc.w)) << 16);
    oB.x = (uint_t)f2bf(fmaf(aB.x, scB, bc.x)) | ((uint_t)f2bf(fmaf(aB.y, scB, bc.y)) << 16);
    oB.y = (uint_t)f2bf(fmaf(aB.z, scB, bc.z)) | ((uint_t)f2bf(fmaf(aB.w, scB, bc.w)) << 16);
    hb[((size_t)p * N_NODES + n0) * 32 + lane]     = oA;
    hb[((size_t)p * N_NODES + n0 + 1) * 32 + lane] = oB;
}

// ---------------- MFMA fc: ALL paths per block; Bs(fcw) staged once ----------------
__global__ __launch_bounds__(256) void fc_mfma_kernel(const ushort_t* __restrict__ hb,
                                                      const ushort_t* __restrict__ fcwb,
                                                      const float* __restrict__ fcb,
                                                      float* __restrict__ partial)
{
    __shared__ ushort_t As[128 * FP];   // 34 KB
    __shared__ ushort_t Bs[128 * FP];   // 34 KB
    __shared__ float red[2][128];
    int m0 = blockIdx.x * 128;
    int t = threadIdx.x;
    int wid = t >> 6, lane = t & 63;
    int wr = wid >> 1, wc = wid & 1;
    int srow = t >> 1, half = (t & 1) * 16;
    int gr = m0 + srow;
    {   // stage Bs once (fcw[o][k] row-major = [n][k])
#pragma unroll
        for (int c = 0; c < 4; ++c) {
            int kb = c * 32 + half;
            const ushort_t* bp = fcwb + (size_t)srow * OUT_F + kb;
            *(uint4*)&Bs[srow * FP + kb]     = *(const uint4*)(bp);
            *(uint4*)&Bs[srow * FP + kb + 8] = *(const uint4*)(bp + 8);
        }
    }
    for (int p = 0; p < P_PATHS; ++p) {
        __syncthreads();   // prev path reads of As / red done (also covers Bs staging)
        const ushort_t* hp = hb + (size_t)p * N_NODES * OUT_F;
#pragma unroll
        for (int c = 0; c < 4; ++c) {
            int kb = c * 32 + half;
            uint4 w0 = make_uint4(0, 0, 0, 0), w1 = w0;
            if (gr < N_NODES) {
                const ushort_t* ap = hp + (size_t)gr * OUT_F + kb;
                w0 = *(const uint4*)(ap);
                w1 = *(const uint4*)(ap + 8);
            }
            *(uint4*)&As[srow * FP + kb]     = w0;
            *(uint4*)&As[srow * FP + kb + 8] = w1;
        }
        __syncthreads();
        f32x4 acc[4][4] = {};
#pragma unroll
        for (int k0 = 0; k0 < OUT_F; k0 += 32) {
            s16x8 aF[4], bF[4];
            int kk = k0 + (lane >> 4) * 8;
#pragma unroll
            for (int m = 0; m < 4; ++m)
                aF[m] = *(const s16x8*)&As[(wr * 64 + m * 16 + (lane & 15)) * FP + kk];
#pragma unroll
            for (int n = 0; n < 4; ++n)
                bF[n] = *(const s16x8*)&Bs[(wc * 64 + n * 16 + (lane & 15)) * FP + kk];
#pragma unroll
            for (int m = 0; m < 4; ++m)
#pragma unroll
                for (int n = 0; n < 4; ++n)
                    acc[m][n] = __builtin_amdgcn_mfma_f32_16x16x32_bf16(aF[m], bF[n], acc[m][n], 0, 0, 0);
        }
#pragma unroll
        for (int n = 0; n < 4; ++n) {
            int col = wc * 64 + n * 16 + (lane & 15);
            float fb = fcb[col];
            float s = 0.f;
#pragma unroll
            for (int m = 0; m < 4; ++m)
#pragma unroll
                for (int i = 0; i < 4; ++i) {
                    int row = m0 + wr * 64 + m * 16 + (lane >> 4) * 4 + i;
                    if (row < N_NODES) s += fast_tanh(acc[m][n][i] + fb);
                }
            s += __shfl_xor(s, 16);
            s += __shfl_xor(s, 32);
            if (lane < 16) red[wr][col] = s;
        }
        __syncthreads();
        if (t < 128)
            partial[((size_t)p * GBLK + blockIdx.x) * OUT_F + t] = red[0][t] + red[1][t];
    }
}

// ---------------- reduce partials -> sp -> beta softmax ----------------
__global__ __launch_bounds__(512) void beta_reduce_kernel(const float* __restrict__ partial,
                                                          const float* __restrict__ att,
                                                          float* __restrict__ beta)
{
    int t = threadIdx.x;          // 512 = P*128
    int p = t >> 7, c = t & 127;
    float s = 0.f;
    for (int i = 0; i < GBLK; ++i)
        s += partial[((size_t)p * GBLK + i) * OUT_F + c];
    float v = att[p * OUT_F + c] * (s * (1.0f / N_NODES));
    __shared__ float red[512];
    red[t] = v;
    __syncthreads();
    for (int off = 64; off >= 1; off >>= 1) {
        if (c < off) red[t] += red[t + off];
        __syncthreads();
    }
    if (t == 0) {
        float w[P_PATHS], mx = -1e30f;
        for (int q = 0; q < P_PATHS; ++q) { w[q] = red[q * 128]; mx = fmaxf(mx, w[q]); }
        float sum = 0.f;
        for (int q = 0; q < P_PATHS; ++q) { w[q] = expf(w[q] - mx); sum += w[q]; }
        for (int q = 0; q < P_PATHS; ++q) beta[q] = w[q] / sum;
    }
}

// ---------------- out = sum_p beta[p]*h[p] + h_bias ----------------
__global__ void combine_kernel(const uint_t* __restrict__ hb, const float* __restrict__ hbias,
                               const float* __restrict__ beta, float* __restrict__ out)
{
    int idx = blockIdx.x * blockDim.x + threadIdx.x;   // over N*64
    if (idx >= N_NODES * 64) return;
    int n = idx >> 6;
    int w = idx & 63;
    float2 hbv = *(const float2*)(hbias + 2 * w);
    float r0 = hbv.x, r1 = hbv.y;
#pragma unroll
    for (int p = 0; p < P_PATHS; ++p) {
        float bp = beta[p];
        uint_t v = hb[((size_t)p * N_NODES + n) * 64 + w];
        r0 = fmaf(bp, bf2f((ushort_t)v), r0);
        r1 = fmaf(bp, bf2f((ushort_t)(v >> 16)), r1);
    }
    *(float2*)(out + (size_t)n * OUT_F + 2 * w) = make_float2(r0, r1);
}

extern "C" void kernel_launch(void* const* d_in, const int* in_sizes, int n_in,
                              void* d_out, int out_size, void* d_ws, size_t ws_size,
                              hipStream_t stream)
{
    const float* x      = (const float*)d_in[0];
    const float* W      = (const float*)d_in[1];
    const float* b_conv = (const float*)d_in[2];
    const float* att    = (const float*)d_in[3];
    const float* fc_w   = (const float*)d_in[4];
    const float* fc_b   = (const float*)d_in[5];
    const float* h_bias = (const float*)d_in[6];
    const int*   src    = (const int*)d_in[7];
    const int*   dst    = (const int*)d_in[8];
    float* out = (float*)d_out;
    float* ws  = (float*)d_ws;

    // ---- ws layout, total ~132.3 MB ----
    size_t off_rsout   = 0;                                            // P*N f32
    size_t off_partial = off_rsout + (size_t)P_PATHS * N_NODES;        // P*GBLK*128 f32
    size_t off_beta    = off_partial + (size_t)P_PATHS * GBLK * OUT_F;
    size_t off_i32     = (off_beta + 4 + 63) & ~(size_t)63;
    // int region (units of int)
    size_t i_bstart  = 0;                                  // P*NBUCK+1 -> pad 1600
    size_t i_bcursor = 1600;                               // P*NBUCK
    size_t i_bcounts = 3200;                               // P*NBUCK
    size_t i_rsn     = 4800;                               // P*(N+1) -> pad 200064
    size_t i_dhist   = 204864;                             // P*QTR*DSL*Q_W = 2,000,000
    size_t i_ebuf    = i_dhist + (size_t)P_PATHS * QTR * DSL * Q_W;   // P*E
    size_t n_ints    = i_ebuf + (size_t)P_PATHS * E_EDGES;
    size_t off_u16   = off_i32 + ((n_ints + 63) & ~(size_t)63);
    // ushort region (units of ushort)
    size_t u_hb    = 0;                                    // P*N*128
    size_t u_xwb   = u_hb + (size_t)P_PATHS * N_NODES * OUT_F;   // P*N*128
    size_t u_eidx2 = u_xwb + (size_t)P_PATHS * N_NODES * OUT_F;  // P*E
    size_t u_Wt    = u_eidx2 + (size_t)P_PATHS * E_EDGES;        // P*IN*OUT
    size_t u_fcwb  = u_Wt + (size_t)P_PATHS * IN_F * OUT_F;      // OUT*OUT

    float* rsout   = ws + off_rsout;
    float* partial = ws + off_partial;
    float* beta    = ws + off_beta;
    int*   ibase   = (int*)(ws + off_i32);
    int*    bstart  = ibase + i_bstart;
    int*    bcursor = ibase + i_bcursor;
    uint_t* bcounts = (uint_t*)(ibase + i_bcounts);
    int*    rsn     = ibase + i_rsn;
    uint_t* dhist   = (uint_t*)(ibase + i_dhist);
    uint_t* ebuf    = (uint_t*)(ibase + i_ebuf);
    ushort_t* ubase = (ushort_t*)(ws + off_u16);
    ushort_t* hb    = ubase + u_hb;
    ushort_t* xwb   = ubase + u_xwb;
    ushort_t* eidx2 = ubase + u_eidx2;
    ushort_t* Wt    = ubase + u_Wt;
    ushort_t* fcwb  = ubase + u_fcwb;

    // only bucket counters accumulate -> zero each call
    hipMemsetAsync(bcounts, 0, (size_t)P_PATHS * NBUCK * sizeof(uint_t), stream);

    prep_kernel<<<(P_PATHS * IN_F * OUT_F + 255) / 256, 256, 0, stream>>>(W, fc_w, Wt, fcwb);
    deghist_kernel<<<dim3(DSL, QTR + 1, P_PATHS), 256, 0, stream>>>(src, dst, dhist, bcounts);
    rsout_bscan_kernel<<<RSB + 1, 1024, 0, stream>>>(dhist, rsout, bcounts, bstart, bcursor);

    gemm_xall_kernel<<<dim3(GBLK, 2), 256, 0, stream>>>(x, Wt, rsout, xwb);
    bscatter_kernel<<<dim3(NCHUNK, P_PATHS), 256, 0, stream>>>(src, dst, bcursor, ebuf);
    blocal_kernel<<<dim3(NBUCK, P_PATHS), 256, 0, stream>>>(ebuf, bstart, eidx2, rsn);
    gather_kernel<<<dim3(N_NODES / 16, P_PATHS), 256, 0, stream>>>(
        xwb, eidx2, rsn, b_conv, (uint2*)hb);
    fc_mfma_kernel<<<GBLK, 256, 0, stream>>>(hb, fcwb, fc_b, partial);

    beta_reduce_kernel<<<1, 512, 0, stream>>>(partial, att, beta);
    combine_kernel<<<(N_NODES * 64 + 255) / 256, 256, 0, stream>>>(
        (const uint_t*)hb, h_bias, beta, out);
}